// Round 9
// baseline (938.765 us; speedup 1.0000x reference)
//
#include <hip/hip_runtime.h>

using short8  = __attribute__((ext_vector_type(8))) short;
using ushort8 = __attribute__((ext_vector_type(8))) unsigned short;
using us4     = __attribute__((ext_vector_type(4))) unsigned short;
using f32x4   = __attribute__((ext_vector_type(4))) float;

static __device__ __forceinline__ short f2bf(float f) {
  unsigned u = __float_as_uint(f);
  u += 0x7fffu + ((u >> 16) & 1u);   // RNE to bf16
  return (short)(u >> 16);
}
static __device__ __forceinline__ float bf2f(short s) {
  return __uint_as_float(((unsigned)(unsigned short)s) << 16);
}
static __device__ __forceinline__ float us2f(unsigned short s) {
  return __uint_as_float(((unsigned)s) << 16);
}
static __device__ __forceinline__ short8 load8_bf16(const float* __restrict__ p) {
  const f32x4* q = (const f32x4*)p;
  f32x4 a = q[0], b = q[1];
  short8 r;
  r[0]=f2bf(a[0]); r[1]=f2bf(a[1]); r[2]=f2bf(a[2]); r[3]=f2bf(a[3]);
  r[4]=f2bf(b[0]); r[5]=f2bf(b[1]); r[6]=f2bf(b[2]); r[7]=f2bf(b[3]);
  return r;
}
// hi/lo bf16 split: v ~= hi + lo
static __device__ __forceinline__ void split8(const float* p, short8& hi, short8& lo) {
  const f32x4* q = (const f32x4*)p;
  f32x4 a = q[0], b = q[1];
  float v[8] = {a[0],a[1],a[2],a[3],b[0],b[1],b[2],b[3]};
#pragma unroll
  for (int j = 0; j < 8; ++j) {
    short h = f2bf(v[j]);
    hi[j] = h;
    lo[j] = f2bf(v[j] - bf2f(h));
  }
}

// ---------------- node encoder: h = relu(X @ Wn^T + bn), MFMA, A-split ----------------
__global__ __launch_bounds__(256) void node_encode(
    const float* __restrict__ X, const float* __restrict__ Wn,
    const float* __restrict__ bn, float* __restrict__ h,
    unsigned short* __restrict__ hb, int nNodes) {
  int tid = threadIdx.x, lane = tid & 63, w = tid >> 6, lg = lane >> 4, lr = lane & 15;
  short8 bf[4][4];
#pragma unroll
  for (int t = 0; t < 4; ++t)
#pragma unroll
    for (int kk = 0; kk < 4; ++kk)
      bf[t][kk] = load8_bf16(Wn + (t*16+lr)*128 + kk*32 + lg*8);
  float bias[4];
#pragma unroll
  for (int t = 0; t < 4; ++t) bias[t] = bn[t*16+lr];

  int base = blockIdx.x * 64 + w * 16;
  int arow = base + lr;
  int nn = arow < nNodes ? arow : nNodes - 1;
  f32x4 acc[4] = {};
#pragma unroll
  for (int kk = 0; kk < 4; ++kk) {
    short8 aH, aL;
    split8(X + (size_t)nn*128 + kk*32 + lg*8, aH, aL);
#pragma unroll
    for (int t = 0; t < 4; ++t) {
      acc[t] = __builtin_amdgcn_mfma_f32_16x16x32_bf16(aH, bf[t][kk], acc[t], 0, 0, 0);
      acc[t] = __builtin_amdgcn_mfma_f32_16x16x32_bf16(aL, bf[t][kk], acc[t], 0, 0, 0);
    }
  }
#pragma unroll
  for (int t = 0; t < 4; ++t)
#pragma unroll
    for (int i = 0; i < 4; ++i) {
      int orow = base + lg*4 + i;
      if (orow < nNodes) {
        float v = fmaxf(acc[t][i] + bias[t], 0.f);
        h[(size_t)orow*64 + t*16 + lr] = v;
        hb[(size_t)orow*64 + t*16 + lr] = (unsigned short)f2bf(v);
      }
    }
}

// ---------------- CSR build (hist + scan; fill fused into edge_mlp) ----------------
__global__ __launch_bounds__(256) void hist_deg(
    const int* __restrict__ dst, int* __restrict__ deg, int nEdges) {
  for (int e = blockIdx.x*256 + threadIdx.x; e < nEdges; e += gridDim.x*256)
    atomicAdd(&deg[dst[e]], 1);
}

__global__ __launch_bounds__(256) void scan_pass1(
    const int* __restrict__ deg, int* __restrict__ bsum, int n) {
  int b = blockIdx.x, tid = threadIdx.x;
  int base = b * 4096;
  int s = 0;
  for (int j = tid; j < 4096; j += 256) {
    int i = base + j;
    s += (i < n) ? deg[i] : 0;
  }
  __shared__ int ws[4];
#pragma unroll
  for (int o = 32; o; o >>= 1) s += __shfl_down(s, o);
  if ((tid & 63) == 0) ws[tid >> 6] = s;
  __syncthreads();
  if (tid == 0) bsum[b] = ws[0] + ws[1] + ws[2] + ws[3];
}

__global__ void scan_pass2(const int* __restrict__ bsum, int* __restrict__ boff,
                           int* __restrict__ off, int nBlocks, int n) {
  if (threadIdx.x == 0 && blockIdx.x == 0) {
    int run = 0;
    for (int b = 0; b < nBlocks; ++b) { boff[b] = run; run += bsum[b]; }
    off[n] = run;
  }
}

__global__ __launch_bounds__(256) void scan_pass3(
    const int* __restrict__ deg, const int* __restrict__ boff,
    int* __restrict__ off, int n) {
  int b = blockIdx.x, tid = threadIdx.x;
  int lane = tid & 63, w = tid >> 6;
  int base = b * 4096 + tid * 16;
  int d[16], tot = 0;
#pragma unroll
  for (int j = 0; j < 16; ++j) {
    d[j] = (base + j < n) ? deg[base + j] : 0;
    tot += d[j];
  }
  int s = tot;
#pragma unroll
  for (int o = 1; o < 64; o <<= 1) {
    int t = __shfl_up(s, o);
    if (lane >= o) s += t;
  }
  __shared__ int ws[4];
  if (lane == 63) ws[w] = s;
  __syncthreads();
  int wo = 0;
  for (int k = 0; k < 4; ++k) wo += (k < w) ? ws[k] : 0;
  int run = boff[b] + wo + s - tot;
#pragma unroll
  for (int j = 0; j < 16; ++j) {
    if (base + j < n) off[base + j] = run;
    run += d[j];
  }
}

// ---------------- edge MLP: stream EA, MFMA, fused CSR-fill, permuted bf16 enc store ----
// enc feature f = t*16+c is stored at position c*4+t (C-fragment layout, no LDS needed).
// Wce's k-rows are permuted to match in make_combos; seg_sum is permutation-agnostic.
__global__ __launch_bounds__(256) void edge_mlp(
    const float* __restrict__ EA, const float* __restrict__ We,
    const float* __restrict__ be, const int* __restrict__ src,
    const int* __restrict__ dst, const int* __restrict__ off,
    int* __restrict__ cur, int* __restrict__ srcs,
    unsigned short* __restrict__ encb, int nEdges) {
  int tid = threadIdx.x, lane = tid & 63, w = tid >> 6;
  int lr = lane & 15, lg = lane >> 4;

  short8 bf[4][2];
#pragma unroll
  for (int t = 0; t < 4; ++t)
#pragma unroll
    for (int kk = 0; kk < 2; ++kk)
      bf[t][kk] = load8_bf16(We + (t*16+lr)*64 + kk*32 + lg*8);
  float bias[4];
#pragma unroll
  for (int t = 0; t < 4; ++t) bias[t] = be[t*16+lr];

  int e0 = blockIdx.x * 128 + w * 32;   // this wave's 32 edges
  // fused CSR fill: lanes 0..31 handle one edge each
  int pos_reg = 0;
  if (lane < 32) {
    int e = e0 + lane;
    if (e < nEdges) {
      int d = dst[e];
      pos_reg = off[d] + atomicAdd(&cur[d], 1);
      srcs[pos_reg] = src[e];
    }
  }

  int c0 = e0 + lr;      if (c0 >= nEdges) c0 = nEdges - 1;
  int c1 = e0 + 16 + lr; if (c1 >= nEdges) c1 = nEdges - 1;
  const float* p0 = EA + (size_t)c0 * 64;
  const float* p1 = EA + (size_t)c1 * 64;
  f32x4 acc[2][4] = {};
#pragma unroll
  for (int kk = 0; kk < 2; ++kk) {
    short8 a0 = load8_bf16(p0 + kk*32 + lg*8);
    short8 a1 = load8_bf16(p1 + kk*32 + lg*8);
#pragma unroll
    for (int t = 0; t < 4; ++t) {
      acc[0][t] = __builtin_amdgcn_mfma_f32_16x16x32_bf16(a0, bf[t][kk], acc[0][t], 0,0,0);
      acc[1][t] = __builtin_amdgcn_mfma_f32_16x16x32_bf16(a1, bf[t][kk], acc[1][t], 0,0,0);
    }
  }
  // store: lane's column c=lr, 4 t-values contiguous at pos*64 + c*4
#pragma unroll
  for (int b = 0; b < 2; ++b)
#pragma unroll
    for (int i = 0; i < 4; ++i) {
      int rloc = b*16 + lg*4 + i;
      int e = e0 + rloc;
      int pos = __shfl(pos_reg, rloc);
      if (e < nEdges) {
        us4 v;
#pragma unroll
        for (int t = 0; t < 4; ++t)
          v[t] = (unsigned short)f2bf(fmaxf(acc[b][t][i] + bias[t], 0.f));
        *(us4*)(encb + (size_t)pos*64 + lr*4) = v;
      }
    }
}

// ---------------- segment sum: Esum[n] = sum of CONTIGUOUS enc rows ----------------
__global__ __launch_bounds__(256) void seg_sum(
    const unsigned short* __restrict__ encb, const int* __restrict__ off,
    float* __restrict__ Esum, int nNodes) {
  int tid = threadIdx.x, lane = tid & 63, w = tid >> 6;
  int er = lane >> 3, fs = lane & 7;
  int n0 = (blockIdx.x * 4 + w) * 4;
  if (n0 >= nNodes) return;
  int a[4], b[4];
#pragma unroll
  for (int j = 0; j < 4; ++j) {
    int n = n0 + j;
    a[j] = (n < nNodes) ? off[n] : 0;
    b[j] = (n < nNodes) ? off[n + 1] : 0;
  }
  float acc[4][8];
#pragma unroll
  for (int j = 0; j < 4; ++j)
#pragma unroll
    for (int q = 0; q < 8; ++q) acc[j][q] = 0.f;
  int mx = 0;
#pragma unroll
  for (int j = 0; j < 4; ++j) { int c = b[j] - a[j]; if (c > mx) mx = c; }
  for (int t = 0; t < mx; t += 8) {
#pragma unroll
    for (int j = 0; j < 4; ++j) {
      int i0 = a[j] + t + er;
      if (i0 < b[j]) {
        ushort8 v = *(const ushort8*)(encb + (size_t)i0*64 + fs*8);
#pragma unroll
        for (int q = 0; q < 8; ++q) acc[j][q] += us2f(v[q]);
      }
    }
  }
#pragma unroll
  for (int j = 0; j < 4; ++j)
#pragma unroll
    for (int q = 0; q < 8; ++q) {
      float v = acc[j][q];
      v += __shfl_xor(v, 8);
      v += __shfl_xor(v, 16);
      v += __shfl_xor(v, 32);
      acc[j][q] = v;
    }
  if (er == 0) {
#pragma unroll
    for (int j = 0; j < 4; ++j) {
      int n = n0 + j;
      if (n < nNodes) {
        f32x4 lo = {acc[j][0], acc[j][1], acc[j][2], acc[j][3]};
        f32x4 hi = {acc[j][4], acc[j][5], acc[j][6], acc[j][7]};
        *(f32x4*)(Esum + (size_t)n * 64 + fs * 8) = lo;
        *(f32x4*)(Esum + (size_t)n * 64 + fs * 8 + 4) = hi;
      }
    }
  }
}

// ---------------- weight combos (hi/lo bf16 splits; Wce k-rows permuted) ----------------
__global__ __launch_bounds__(256) void make_combos(
    const float* __restrict__ wih, const float* __restrict__ Wagg,
    const float* __restrict__ bagg, const float* __restrict__ whh,
    short* __restrict__ WceH, short* __restrict__ WceL,
    short* __restrict__ WchH, short* __restrict__ WchL,
    short* __restrict__ whhH, short* __restrict__ whhL, float* __restrict__ bihA) {
  int idx = blockIdx.x*256 + threadIdx.x;
  if (idx < 12288) {
    int r = idx >> 6, k = idx & 63;
    float a = 0.f, b = 0.f;
    for (int j = 0; j < 64; ++j) {
      float ww = wih[r*64 + j];
      a += ww * Wagg[j*128 + k];
      b += ww * Wagg[j*128 + 64 + k];
    }
    short ah = f2bf(a);
    WchH[idx] = ah; WchL[idx] = f2bf(a - bf2f(ah));
    // Esum is stored feature-permuted (f -> (f&15)*4 + (f>>4)); permute Wce rows to match
    int kp = (k & 15) * 4 + (k >> 4);
    short bh = f2bf(b);
    WceH[r*64 + kp] = bh; WceL[r*64 + kp] = f2bf(b - bf2f(bh));
    float wv = whh[idx];
    short hh = f2bf(wv);
    whhH[idx] = hh; whhL[idx] = f2bf(wv - bf2f(hh));
    if (idx < 192) {
      float s = 0.f;
      for (int j = 0; j < 64; ++j) s += wih[idx*64 + j] * bagg[j];
      bihA[idx] = s;
    }
  }
}

// ---------------- fused layer: er/fs gather -> LDS, then MFMA (gi & gh) + GRU ----------
__global__ __launch_bounds__(256) void layer_fused(
    const float* __restrict__ h_old, const unsigned short* __restrict__ h_oldb,
    const float* __restrict__ Esum,
    const int* __restrict__ off, const int* __restrict__ srcs,
    const int* __restrict__ deg,
    const short* __restrict__ WceH, const short* __restrict__ WceL,
    const short* __restrict__ WchH, const short* __restrict__ WchL,
    const short* __restrict__ whhH, const short* __restrict__ whhL,
    const float* __restrict__ bihA, const float* __restrict__ bih,
    const float* __restrict__ bhh, float* __restrict__ h_new,
    unsigned short* __restrict__ h_newb, int nNodes) {
  __shared__ float G[64][68];
  int tid = threadIdx.x, lane = tid & 63, w = tid >> 6;
  int lr = lane & 15, lg = lane >> 4;
  int er = lane >> 3, fs = lane & 7;
  int nb = blockIdx.x * 64;

  // ---- gather phase: wave w gathers rows for nodes nb+w*16 .. +15 (4 groups of 4) ----
  for (int g = 0; g < 4; ++g) {
    int n0 = nb + w*16 + g*4;
    int a[4], b[4];
#pragma unroll
    for (int j = 0; j < 4; ++j) {
      int n = n0 + j;
      a[j] = (n < nNodes) ? off[n] : 0;
      b[j] = (n < nNodes) ? off[n + 1] : 0;
    }
    float acc[4][8];
#pragma unroll
    for (int j = 0; j < 4; ++j)
#pragma unroll
      for (int q = 0; q < 8; ++q) acc[j][q] = 0.f;
    int mx = 0;
#pragma unroll
    for (int j = 0; j < 4; ++j) { int c = b[j] - a[j]; if (c > mx) mx = c; }
    for (int t = 0; t < mx; t += 16) {
      int s0[4], s1[4];
      bool m0[4], m1[4];
#pragma unroll
      for (int j = 0; j < 4; ++j) {
        int i0 = a[j] + t + er, i1 = i0 + 8;
        int bm = b[j] - 1;
        m0[j] = i0 < b[j]; m1[j] = i1 < b[j];
        int c0 = m0[j] ? i0 : (bm > a[j] ? bm : a[j]);
        int c1 = m1[j] ? i1 : c0;
        s0[j] = (b[j] > a[j]) ? srcs[c0] : 0;
        s1[j] = (b[j] > a[j]) ? srcs[c1] : 0;
      }
#pragma unroll
      for (int j = 0; j < 4; ++j) {
        ushort8 v0 = *(const ushort8*)(h_oldb + (size_t)s0[j] * 64 + fs * 8);
        ushort8 v1 = *(const ushort8*)(h_oldb + (size_t)s1[j] * 64 + fs * 8);
        if (m0[j]) {
#pragma unroll
          for (int q = 0; q < 8; ++q) acc[j][q] += us2f(v0[q]);
        }
        if (m1[j]) {
#pragma unroll
          for (int q = 0; q < 8; ++q) acc[j][q] += us2f(v1[q]);
        }
      }
    }
#pragma unroll
    for (int j = 0; j < 4; ++j)
#pragma unroll
      for (int q = 0; q < 8; ++q) {
        float v = acc[j][q];
        v += __shfl_xor(v, 8);
        v += __shfl_xor(v, 16);
        v += __shfl_xor(v, 32);
        acc[j][q] = v;
      }
    if (er == 0) {
#pragma unroll
      for (int j = 0; j < 4; ++j) {
        int rloc = w*16 + g*4 + j;
        f32x4 lo = {acc[j][0], acc[j][1], acc[j][2], acc[j][3]};
        f32x4 hi = {acc[j][4], acc[j][5], acc[j][6], acc[j][7]};
        *(f32x4*)(&G[rloc][fs*8]) = lo;
        *(f32x4*)(&G[rloc][fs*8 + 4]) = hi;
      }
    }
  }
  __syncthreads();

  // ---- dense phase ----
  int arow = nb + w*16 + lr; if (arow >= nNodes) arow = nNodes - 1;
  short8 EsH[2], EsL[2], GHf[2], GLf[2], HH[2], HL[2];
#pragma unroll
  for (int kk = 0; kk < 2; ++kk) {
    split8(Esum + (size_t)arow*64 + kk*32 + lg*8, EsH[kk], EsL[kk]);
    split8(&G[w*16 + lr][kk*32 + lg*8], GHf[kk], GLf[kk]);
    split8(h_old + (size_t)arow*64 + kk*32 + lg*8, HH[kk], HL[kk]);
  }

  int row0 = nb + w*16 + lg*4;
  float degv[4];
#pragma unroll
  for (int i = 0; i < 4; ++i) {
    int n = row0 + i;
    degv[i] = (n < nNodes) ? (float)deg[n] : 0.f;
  }

  f32x4 gi[12], gh[12];
#pragma unroll
  for (int ct = 0; ct < 12; ++ct) {
    float bi = bih[ct*16 + lr], ba = bihA[ct*16 + lr], bh = bhh[ct*16 + lr];
#pragma unroll
    for (int i = 0; i < 4; ++i) { gi[ct][i] = bi + degv[i]*ba; gh[ct][i] = bh; }
  }

#pragma unroll
  for (int ct = 0; ct < 12; ++ct) {
    int wb = (ct*16 + lr)*64 + lg*8;
#pragma unroll
    for (int kk = 0; kk < 2; ++kk) {
      int o = wb + kk*32;
      short8 wceh = *(const short8*)(WceH + o);
      short8 wcel = *(const short8*)(WceL + o);
      short8 wchh = *(const short8*)(WchH + o);
      short8 wchl = *(const short8*)(WchL + o);
      short8 whh_h = *(const short8*)(whhH + o);
      short8 whh_l = *(const short8*)(whhL + o);
      gi[ct] = __builtin_amdgcn_mfma_f32_16x16x32_bf16(EsH[kk], wceh, gi[ct], 0,0,0);
      gi[ct] = __builtin_amdgcn_mfma_f32_16x16x32_bf16(EsL[kk], wceh, gi[ct], 0,0,0);
      gi[ct] = __builtin_amdgcn_mfma_f32_16x16x32_bf16(EsH[kk], wcel, gi[ct], 0,0,0);
      gi[ct] = __builtin_amdgcn_mfma_f32_16x16x32_bf16(GHf[kk], wchh, gi[ct], 0,0,0);
      gi[ct] = __builtin_amdgcn_mfma_f32_16x16x32_bf16(GLf[kk], wchh, gi[ct], 0,0,0);
      gi[ct] = __builtin_amdgcn_mfma_f32_16x16x32_bf16(GHf[kk], wchl, gi[ct], 0,0,0);
      gh[ct] = __builtin_amdgcn_mfma_f32_16x16x32_bf16(HH[kk], whh_h, gh[ct], 0,0,0);
      gh[ct] = __builtin_amdgcn_mfma_f32_16x16x32_bf16(HL[kk], whh_h, gh[ct], 0,0,0);
      gh[ct] = __builtin_amdgcn_mfma_f32_16x16x32_bf16(HH[kk], whh_l, gh[ct], 0,0,0);
    }
  }

#pragma unroll
  for (int ct = 0; ct < 4; ++ct)
#pragma unroll
    for (int i = 0; i < 4; ++i) {
      int n = row0 + i;
      if (n < nNodes) {
        int jh = ct*16 + lr;
        float r = 1.f/(1.f + expf(-(gi[ct][i] + gh[ct][i])));
        float z = 1.f/(1.f + expf(-(gi[ct+4][i] + gh[ct+4][i])));
        float nn = tanhf(gi[ct+8][i] + r * gh[ct+8][i]);
        float hv = h_old[(size_t)n*64 + jh];
        float hn = (1.f - z)*nn + z*hv;
        h_new[(size_t)n*64 + jh] = hn;
        h_newb[(size_t)n*64 + jh] = (unsigned short)f2bf(hn);
      }
    }
}

__global__ __launch_bounds__(256) void out_mlp(
    const float* __restrict__ h, const int* __restrict__ pm,
    const float* __restrict__ W1, const float* __restrict__ b1,
    const float* __restrict__ W2, const float* __restrict__ b2,
    float* __restrict__ out, int nPosts) {
  int tid = threadIdx.x;
  int lane = tid & 63;
  int p = blockIdx.x*4 + (tid >> 6);
  if (p >= nPosts) return;
  int n = pm[p];
  float v = h[(size_t)n*64 + lane];
  int row = lane & 31;
  float o = b1[row];
#pragma unroll
  for (int k = 0; k < 64; ++k) {
    float vb = __shfl(v, k);
    o += vb * W1[row*64 + k];
  }
  o = fmaxf(o, 0.f);
  float val = o * W2[row] * 0.5f;  // each row computed twice -> halve
#pragma unroll
  for (int offm = 32; offm > 0; offm >>= 1) val += __shfl_xor(val, offm);
  if (lane == 0) out[p] = 1.f/(1.f + expf(-(val + b2[0])));
}

static inline char* aln(char*& w, size_t bytes) {
  uintptr_t p = ((uintptr_t)w + 255) & ~(uintptr_t)255;
  char* r = (char*)p;
  w = r + bytes;
  return r;
}

extern "C" void kernel_launch(void* const* d_in, const int* in_sizes, int n_in,
                              void* d_out, int out_size, void* d_ws, size_t ws_size,
                              hipStream_t stream) {
  const float* X    = (const float*)d_in[0];
  const float* EA   = (const float*)d_in[1];
  const int*   EI   = (const int*)d_in[2];
  const int*   PM   = (const int*)d_in[3];
  const float* Wn   = (const float*)d_in[5];
  const float* bn   = (const float*)d_in[6];
  const float* We   = (const float*)d_in[7];
  const float* be   = (const float*)d_in[8];
  const float* Wagg = (const float*)d_in[9];
  const float* bagg = (const float*)d_in[10];
  const float* wih  = (const float*)d_in[11];
  const float* whh  = (const float*)d_in[12];
  const float* bih  = (const float*)d_in[13];
  const float* bhh  = (const float*)d_in[14];
  const float* W1   = (const float*)d_in[15];
  const float* b1   = (const float*)d_in[16];
  const float* W2   = (const float*)d_in[17];
  const float* b2   = (const float*)d_in[18];
  float* out = (float*)d_out;

  int nNodes = in_sizes[0] / 128;
  int nEdges = in_sizes[1] / 64;
  int nPosts = in_sizes[3];
  const int* src = EI;
  const int* dst = EI + nEdges;
  int nSB = (nNodes + 4095) / 4096;

  char* w = (char*)d_ws;
  float* h0   = (float*)aln(w, (size_t)nNodes * 64 * 4);
  float* h1   = (float*)aln(w, (size_t)nNodes * 64 * 4);
  unsigned short* h0b = (unsigned short*)aln(w, (size_t)nNodes * 64 * 2);
  unsigned short* h1b = (unsigned short*)aln(w, (size_t)nNodes * 64 * 2);
  float* Esum = (float*)aln(w, (size_t)nNodes * 64 * 4);
  short* WceH = (short*)aln(w, 12288 * 2);
  short* WceL = (short*)aln(w, 12288 * 2);
  short* WchH = (short*)aln(w, 12288 * 2);
  short* WchL = (short*)aln(w, 12288 * 2);
  short* whhH = (short*)aln(w, 12288 * 2);
  short* whhL = (short*)aln(w, 12288 * 2);
  float* bihA = (float*)aln(w, 192 * 4);
  int*   off  = (int*)aln(w, (size_t)(nNodes + 1) * 4);
  int*   deg  = (int*)aln(w, (size_t)nNodes * 4);
  int*   cur  = (int*)aln(w, (size_t)nNodes * 4);
  int*   srcs = (int*)aln(w, (size_t)nEdges * 4);
  int*   bsum = (int*)aln(w, (size_t)nSB * 4);
  int*   boff = (int*)aln(w, (size_t)nSB * 4);
  unsigned short* encb = (unsigned short*)aln(w, (size_t)nEdges * 64 * 2);

  hipMemsetAsync(deg, 0, (size_t)nNodes * 4, stream);
  hipMemsetAsync(cur, 0, (size_t)nNodes * 4, stream);

  hist_deg<<<2048, 256, 0, stream>>>(dst, deg, nEdges);
  scan_pass1<<<nSB, 256, 0, stream>>>(deg, bsum, nNodes);
  scan_pass2<<<1, 1, 0, stream>>>(bsum, boff, off, nSB, nNodes);
  scan_pass3<<<nSB, 256, 0, stream>>>(deg, boff, off, nNodes);

  node_encode<<<(nNodes + 63) / 64, 256, 0, stream>>>(X, Wn, bn, h0, h0b, nNodes);
  edge_mlp<<<(nEdges + 127) / 128, 256, 0, stream>>>(EA, We, be, src, dst, off, cur,
                                                     srcs, encb, nEdges);
  seg_sum<<<(nNodes + 15) / 16, 256, 0, stream>>>(encb, off, Esum, nNodes);
  make_combos<<<48, 256, 0, stream>>>(wih, Wagg, bagg, whh,
                                      WceH, WceL, WchH, WchL, whhH, whhL, bihA);

  // layer 1
  layer_fused<<<(nNodes + 63) / 64, 256, 0, stream>>>(
      h0, h0b, Esum, off, srcs, deg, WceH, WceL, WchH, WchL, whhH, whhL,
      bihA, bih, bhh, h1, h1b, nNodes);
  // layer 2
  layer_fused<<<(nNodes + 63) / 64, 256, 0, stream>>>(
      h1, h1b, Esum, off, srcs, deg, WceH, WceL, WchH, WchL, whhH, whhL,
      bihA, bih, bhh, h0, h0b, nNodes);

  out_mlp<<<(nPosts + 3) / 4, 256, 0, stream>>>(h0, PM, W1, b1, W2, b2, out, nPosts);
}

// Round 10
// 781.896 us; speedup vs baseline: 1.2006x; 1.2006x over previous
//
#include <hip/hip_runtime.h>

using short8  = __attribute__((ext_vector_type(8))) short;
using ushort8 = __attribute__((ext_vector_type(8))) unsigned short;
using us4     = __attribute__((ext_vector_type(4))) unsigned short;
using f32x4   = __attribute__((ext_vector_type(4))) float;

static __device__ __forceinline__ short f2bf(float f) {
  unsigned u = __float_as_uint(f);
  u += 0x7fffu + ((u >> 16) & 1u);   // RNE to bf16
  return (short)(u >> 16);
}
static __device__ __forceinline__ float bf2f(short s) {
  return __uint_as_float(((unsigned)(unsigned short)s) << 16);
}
static __device__ __forceinline__ float us2f(unsigned short s) {
  return __uint_as_float(((unsigned)s) << 16);
}
static __device__ __forceinline__ short8 load8_bf16(const float* __restrict__ p) {
  const f32x4* q = (const f32x4*)p;
  f32x4 a = q[0], b = q[1];
  short8 r;
  r[0]=f2bf(a[0]); r[1]=f2bf(a[1]); r[2]=f2bf(a[2]); r[3]=f2bf(a[3]);
  r[4]=f2bf(b[0]); r[5]=f2bf(b[1]); r[6]=f2bf(b[2]); r[7]=f2bf(b[3]);
  return r;
}
// hi/lo bf16 split: v ~= hi + lo
static __device__ __forceinline__ void split8(const float* p, short8& hi, short8& lo) {
  const f32x4* q = (const f32x4*)p;
  f32x4 a = q[0], b = q[1];
  float v[8] = {a[0],a[1],a[2],a[3],b[0],b[1],b[2],b[3]};
#pragma unroll
  for (int j = 0; j < 8; ++j) {
    short h = f2bf(v[j]);
    hi[j] = h;
    lo[j] = f2bf(v[j] - bf2f(h));
  }
}

// ---------------- node encoder: h = relu(X @ Wn^T + bn), MFMA, A-split ----------------
__global__ __launch_bounds__(256) void node_encode(
    const float* __restrict__ X, const float* __restrict__ Wn,
    const float* __restrict__ bn, float* __restrict__ h,
    unsigned short* __restrict__ hb, int nNodes) {
  int tid = threadIdx.x, lane = tid & 63, w = tid >> 6, lg = lane >> 4, lr = lane & 15;
  short8 bf[4][4];
#pragma unroll
  for (int t = 0; t < 4; ++t)
#pragma unroll
    for (int kk = 0; kk < 4; ++kk)
      bf[t][kk] = load8_bf16(Wn + (t*16+lr)*128 + kk*32 + lg*8);
  float bias[4];
#pragma unroll
  for (int t = 0; t < 4; ++t) bias[t] = bn[t*16+lr];

  int base = blockIdx.x * 64 + w * 16;
  int arow = base + lr;
  int nn = arow < nNodes ? arow : nNodes - 1;
  f32x4 acc[4] = {};
#pragma unroll
  for (int kk = 0; kk < 4; ++kk) {
    short8 aH, aL;
    split8(X + (size_t)nn*128 + kk*32 + lg*8, aH, aL);
#pragma unroll
    for (int t = 0; t < 4; ++t) {
      acc[t] = __builtin_amdgcn_mfma_f32_16x16x32_bf16(aH, bf[t][kk], acc[t], 0, 0, 0);
      acc[t] = __builtin_amdgcn_mfma_f32_16x16x32_bf16(aL, bf[t][kk], acc[t], 0, 0, 0);
    }
  }
#pragma unroll
  for (int t = 0; t < 4; ++t)
#pragma unroll
    for (int i = 0; i < 4; ++i) {
      int orow = base + lg*4 + i;
      if (orow < nNodes) {
        float v = fmaxf(acc[t][i] + bias[t], 0.f);
        h[(size_t)orow*64 + t*16 + lr] = v;
        hb[(size_t)orow*64 + t*16 + lr] = (unsigned short)f2bf(v);
      }
    }
}

// ---------------- CSR build (hist + scan; fill fused into edge_mlp) ----------------
__global__ __launch_bounds__(256) void hist_deg(
    const int* __restrict__ dst, int* __restrict__ deg, int nEdges) {
  for (int e = blockIdx.x*256 + threadIdx.x; e < nEdges; e += gridDim.x*256)
    atomicAdd(&deg[dst[e]], 1);
}

__global__ __launch_bounds__(256) void scan_pass1(
    const int* __restrict__ deg, int* __restrict__ bsum, int n) {
  int b = blockIdx.x, tid = threadIdx.x;
  int base = b * 4096;
  int s = 0;
  for (int j = tid; j < 4096; j += 256) {
    int i = base + j;
    s += (i < n) ? deg[i] : 0;
  }
  __shared__ int ws[4];
#pragma unroll
  for (int o = 32; o; o >>= 1) s += __shfl_down(s, o);
  if ((tid & 63) == 0) ws[tid >> 6] = s;
  __syncthreads();
  if (tid == 0) bsum[b] = ws[0] + ws[1] + ws[2] + ws[3];
}

__global__ void scan_pass2(const int* __restrict__ bsum, int* __restrict__ boff,
                           int* __restrict__ off, int nBlocks, int n) {
  if (threadIdx.x == 0 && blockIdx.x == 0) {
    int run = 0;
    for (int b = 0; b < nBlocks; ++b) { boff[b] = run; run += bsum[b]; }
    off[n] = run;
  }
}

__global__ __launch_bounds__(256) void scan_pass3(
    const int* __restrict__ deg, const int* __restrict__ boff,
    int* __restrict__ off, int n) {
  int b = blockIdx.x, tid = threadIdx.x;
  int lane = tid & 63, w = tid >> 6;
  int base = b * 4096 + tid * 16;
  int d[16], tot = 0;
#pragma unroll
  for (int j = 0; j < 16; ++j) {
    d[j] = (base + j < n) ? deg[base + j] : 0;
    tot += d[j];
  }
  int s = tot;
#pragma unroll
  for (int o = 1; o < 64; o <<= 1) {
    int t = __shfl_up(s, o);
    if (lane >= o) s += t;
  }
  __shared__ int ws[4];
  if (lane == 63) ws[w] = s;
  __syncthreads();
  int wo = 0;
  for (int k = 0; k < 4; ++k) wo += (k < w) ? ws[k] : 0;
  int run = boff[b] + wo + s - tot;
#pragma unroll
  for (int j = 0; j < 16; ++j) {
    if (base + j < n) off[base + j] = run;
    run += d[j];
  }
}

// ---------------- edge MLP: stream EA, MFMA, fused CSR-fill, permuted bf16 enc store ----
__global__ __launch_bounds__(256) void edge_mlp(
    const float* __restrict__ EA, const float* __restrict__ We,
    const float* __restrict__ be, const int* __restrict__ src,
    const int* __restrict__ dst, const int* __restrict__ off,
    int* __restrict__ cur, int* __restrict__ srcs,
    unsigned short* __restrict__ encb, int nEdges) {
  int tid = threadIdx.x, lane = tid & 63, w = tid >> 6;
  int lr = lane & 15, lg = lane >> 4;

  short8 bf[4][2];
#pragma unroll
  for (int t = 0; t < 4; ++t)
#pragma unroll
    for (int kk = 0; kk < 2; ++kk)
      bf[t][kk] = load8_bf16(We + (t*16+lr)*64 + kk*32 + lg*8);
  float bias[4];
#pragma unroll
  for (int t = 0; t < 4; ++t) bias[t] = be[t*16+lr];

  int e0 = blockIdx.x * 128 + w * 32;   // this wave's 32 edges
  int pos_reg = 0;
  if (lane < 32) {
    int e = e0 + lane;
    if (e < nEdges) {
      int d = dst[e];
      pos_reg = off[d] + atomicAdd(&cur[d], 1);
      srcs[pos_reg] = src[e];
    }
  }

  int c0 = e0 + lr;      if (c0 >= nEdges) c0 = nEdges - 1;
  int c1 = e0 + 16 + lr; if (c1 >= nEdges) c1 = nEdges - 1;
  const float* p0 = EA + (size_t)c0 * 64;
  const float* p1 = EA + (size_t)c1 * 64;
  f32x4 acc[2][4] = {};
#pragma unroll
  for (int kk = 0; kk < 2; ++kk) {
    short8 a0 = load8_bf16(p0 + kk*32 + lg*8);
    short8 a1 = load8_bf16(p1 + kk*32 + lg*8);
#pragma unroll
    for (int t = 0; t < 4; ++t) {
      acc[0][t] = __builtin_amdgcn_mfma_f32_16x16x32_bf16(a0, bf[t][kk], acc[0][t], 0,0,0);
      acc[1][t] = __builtin_amdgcn_mfma_f32_16x16x32_bf16(a1, bf[t][kk], acc[1][t], 0,0,0);
    }
  }
#pragma unroll
  for (int b = 0; b < 2; ++b)
#pragma unroll
    for (int i = 0; i < 4; ++i) {
      int rloc = b*16 + lg*4 + i;
      int e = e0 + rloc;
      int pos = __shfl(pos_reg, rloc);
      if (e < nEdges) {
        us4 v;
#pragma unroll
        for (int t = 0; t < 4; ++t)
          v[t] = (unsigned short)f2bf(fmaxf(acc[b][t][i] + bias[t], 0.f));
        *(us4*)(encb + (size_t)pos*64 + lr*4) = v;
      }
    }
}

// ---------------- segment sum: contiguous enc rows, 2-deep unrolled ----------------
__global__ __launch_bounds__(256) void seg_sum(
    const unsigned short* __restrict__ encb, const int* __restrict__ off,
    float* __restrict__ Esum, int nNodes) {
  int tid = threadIdx.x, lane = tid & 63, w = tid >> 6;
  int er = lane >> 3, fs = lane & 7;
  int n0 = (blockIdx.x * 4 + w) * 4;
  if (n0 >= nNodes) return;
  int a[4], b[4];
#pragma unroll
  for (int j = 0; j < 4; ++j) {
    int n = n0 + j;
    a[j] = (n < nNodes) ? off[n] : 0;
    b[j] = (n < nNodes) ? off[n + 1] : 0;
  }
  float acc[4][8];
#pragma unroll
  for (int j = 0; j < 4; ++j)
#pragma unroll
    for (int q = 0; q < 8; ++q) acc[j][q] = 0.f;
  int mx = 0;
#pragma unroll
  for (int j = 0; j < 4; ++j) { int c = b[j] - a[j]; if (c > mx) mx = c; }
  for (int t = 0; t < mx; t += 16) {
    ushort8 v0[4], v1[4];
#pragma unroll
    for (int j = 0; j < 4; ++j) {
      int i0 = a[j] + t + er, i1 = i0 + 8;
      int c0 = (i0 < b[j]) ? i0 : 0;
      int c1 = (i1 < b[j]) ? i1 : 0;
      v0[j] = *(const ushort8*)(encb + (size_t)c0*64 + fs*8);
      v1[j] = *(const ushort8*)(encb + (size_t)c1*64 + fs*8);
    }
#pragma unroll
    for (int j = 0; j < 4; ++j) {
      int i0 = a[j] + t + er, i1 = i0 + 8;
      if (i0 < b[j]) {
#pragma unroll
        for (int q = 0; q < 8; ++q) acc[j][q] += us2f(v0[j][q]);
      }
      if (i1 < b[j]) {
#pragma unroll
        for (int q = 0; q < 8; ++q) acc[j][q] += us2f(v1[j][q]);
      }
    }
  }
#pragma unroll
  for (int j = 0; j < 4; ++j)
#pragma unroll
    for (int q = 0; q < 8; ++q) {
      float v = acc[j][q];
      v += __shfl_xor(v, 8);
      v += __shfl_xor(v, 16);
      v += __shfl_xor(v, 32);
      acc[j][q] = v;
    }
  if (er == 0) {
#pragma unroll
    for (int j = 0; j < 4; ++j) {
      int n = n0 + j;
      if (n < nNodes) {
        f32x4 lo = {acc[j][0], acc[j][1], acc[j][2], acc[j][3]};
        f32x4 hi = {acc[j][4], acc[j][5], acc[j][6], acc[j][7]};
        *(f32x4*)(Esum + (size_t)n * 64 + fs * 8) = lo;
        *(f32x4*)(Esum + (size_t)n * 64 + fs * 8 + 4) = hi;
      }
    }
  }
}

// ---------------- weight combos (hi/lo bf16 splits; Wce k-rows permuted) ----------------
__global__ __launch_bounds__(256) void make_combos(
    const float* __restrict__ wih, const float* __restrict__ Wagg,
    const float* __restrict__ bagg, const float* __restrict__ whh,
    short* __restrict__ WceH, short* __restrict__ WceL,
    short* __restrict__ WchH, short* __restrict__ WchL,
    short* __restrict__ whhH, short* __restrict__ whhL, float* __restrict__ bihA) {
  int idx = blockIdx.x*256 + threadIdx.x;
  if (idx < 12288) {
    int r = idx >> 6, k = idx & 63;
    float a = 0.f, b = 0.f;
    for (int j = 0; j < 64; ++j) {
      float ww = wih[r*64 + j];
      a += ww * Wagg[j*128 + k];
      b += ww * Wagg[j*128 + 64 + k];
    }
    short ah = f2bf(a);
    WchH[idx] = ah; WchL[idx] = f2bf(a - bf2f(ah));
    int kp = (k & 15) * 4 + (k >> 4);
    short bh = f2bf(b);
    WceH[r*64 + kp] = bh; WceL[r*64 + kp] = f2bf(b - bf2f(bh));
    float wv = whh[idx];
    short hh = f2bf(wv);
    whhH[idx] = hh; whhL[idx] = f2bf(wv - bf2f(hh));
    if (idx < 192) {
      float s = 0.f;
      for (int j = 0; j < 64; ++j) s += wih[idx*64 + j] * bagg[j];
      bihA[idx] = s;
    }
  }
}

// ---------------- h gather: software-pipelined (prefetch next srcs under gathers) -------
__global__ __launch_bounds__(256) void gather_G(
    const unsigned short* __restrict__ hb, const int* __restrict__ off,
    const int* __restrict__ srcs, float* __restrict__ G, int nNodes) {
  int tid = threadIdx.x, lane = tid & 63, w = tid >> 6;
  int er = lane >> 3, fs = lane & 7;
  int n0 = (blockIdx.x * 4 + w) * 4;
  if (n0 >= nNodes) return;
  int a[4], b[4];
#pragma unroll
  for (int j = 0; j < 4; ++j) {
    int n = n0 + j;
    a[j] = (n < nNodes) ? off[n] : 0;
    b[j] = (n < nNodes) ? off[n + 1] : 0;
  }
  float acc[4][8];
#pragma unroll
  for (int j = 0; j < 4; ++j)
#pragma unroll
    for (int q = 0; q < 8; ++q) acc[j][q] = 0.f;
  int mx = 0;
#pragma unroll
  for (int j = 0; j < 4; ++j) { int c = b[j] - a[j]; if (c > mx) mx = c; }

  int s0[4], s1[4];
  // prologue: indices for t=0
#pragma unroll
  for (int j = 0; j < 4; ++j) {
    int i0 = a[j] + er, i1 = i0 + 8;
    int c0 = (i0 < b[j]) ? i0 : 0;
    int c1 = (i1 < b[j]) ? i1 : 0;
    bool any = b[j] > a[j];
    s0[j] = any ? srcs[c0] : 0;
    s1[j] = any ? srcs[c1] : 0;
  }
  for (int t = 0; t < mx; t += 16) {
    // issue gathers for current indices
    ushort8 v0[4], v1[4];
#pragma unroll
    for (int j = 0; j < 4; ++j) {
      v0[j] = *(const ushort8*)(hb + (size_t)s0[j] * 64 + fs * 8);
      v1[j] = *(const ushort8*)(hb + (size_t)s1[j] * 64 + fs * 8);
    }
    // prefetch next iteration's indices while gathers are in flight
    int p0[4], p1[4];
    if (t + 16 < mx) {
#pragma unroll
      for (int j = 0; j < 4; ++j) {
        int i0 = a[j] + t + 16 + er, i1 = i0 + 8;
        int c0 = (i0 < b[j]) ? i0 : 0;
        int c1 = (i1 < b[j]) ? i1 : 0;
        bool any = b[j] > a[j];
        p0[j] = any ? srcs[c0] : 0;
        p1[j] = any ? srcs[c1] : 0;
      }
    } else {
#pragma unroll
      for (int j = 0; j < 4; ++j) { p0[j] = 0; p1[j] = 0; }
    }
    // accumulate (masked)
#pragma unroll
    for (int j = 0; j < 4; ++j) {
      int i0 = a[j] + t + er, i1 = i0 + 8;
      if (i0 < b[j]) {
#pragma unroll
        for (int q = 0; q < 8; ++q) acc[j][q] += us2f(v0[j][q]);
      }
      if (i1 < b[j]) {
#pragma unroll
        for (int q = 0; q < 8; ++q) acc[j][q] += us2f(v1[j][q]);
      }
    }
#pragma unroll
    for (int j = 0; j < 4; ++j) { s0[j] = p0[j]; s1[j] = p1[j]; }
  }
#pragma unroll
  for (int j = 0; j < 4; ++j)
#pragma unroll
    for (int q = 0; q < 8; ++q) {
      float v = acc[j][q];
      v += __shfl_xor(v, 8);
      v += __shfl_xor(v, 16);
      v += __shfl_xor(v, 32);
      acc[j][q] = v;
    }
  if (er == 0) {
#pragma unroll
    for (int j = 0; j < 4; ++j) {
      int n = n0 + j;
      if (n < nNodes) {
        f32x4 lo = {acc[j][0], acc[j][1], acc[j][2], acc[j][3]};
        f32x4 hi = {acc[j][4], acc[j][5], acc[j][6], acc[j][7]};
        *(f32x4*)(G + (size_t)n * 64 + fs * 8) = lo;
        *(f32x4*)(G + (size_t)n * 64 + fs * 8 + 4) = hi;
      }
    }
  }
}

// ---------------- dense layer: MFMA (gi & gh) + GRU, fully streaming ----------------
__global__ __launch_bounds__(256) void layer_dense(
    const float* __restrict__ h_old, const float* __restrict__ Esum,
    const float* __restrict__ G, const int* __restrict__ deg,
    const short* __restrict__ WceH, const short* __restrict__ WceL,
    const short* __restrict__ WchH, const short* __restrict__ WchL,
    const short* __restrict__ whhH, const short* __restrict__ whhL,
    const float* __restrict__ bihA, const float* __restrict__ bih,
    const float* __restrict__ bhh, float* __restrict__ h_new,
    unsigned short* __restrict__ h_newb, int nNodes) {
  int tid = threadIdx.x, lane = tid & 63, w = tid >> 6;
  int lr = lane & 15, lg = lane >> 4;
  int nb = blockIdx.x * 64;

  int arow = nb + w*16 + lr; if (arow >= nNodes) arow = nNodes - 1;
  short8 EsH[2], EsL[2], GHf[2], GLf[2], HH[2], HL[2];
#pragma unroll
  for (int kk = 0; kk < 2; ++kk) {
    split8(Esum + (size_t)arow*64 + kk*32 + lg*8, EsH[kk], EsL[kk]);
    split8(G + (size_t)arow*64 + kk*32 + lg*8, GHf[kk], GLf[kk]);
    split8(h_old + (size_t)arow*64 + kk*32 + lg*8, HH[kk], HL[kk]);
  }

  int row0 = nb + w*16 + lg*4;
  float degv[4];
#pragma unroll
  for (int i = 0; i < 4; ++i) {
    int n = row0 + i;
    degv[i] = (n < nNodes) ? (float)deg[n] : 0.f;
  }

  f32x4 gi[12], gh[12];
#pragma unroll
  for (int ct = 0; ct < 12; ++ct) {
    float bi = bih[ct*16 + lr], ba = bihA[ct*16 + lr], bh = bhh[ct*16 + lr];
#pragma unroll
    for (int i = 0; i < 4; ++i) { gi[ct][i] = bi + degv[i]*ba; gh[ct][i] = bh; }
  }

#pragma unroll
  for (int ct = 0; ct < 12; ++ct) {
    int wb = (ct*16 + lr)*64 + lg*8;
#pragma unroll
    for (int kk = 0; kk < 2; ++kk) {
      int o = wb + kk*32;
      short8 wceh = *(const short8*)(WceH + o);
      short8 wcel = *(const short8*)(WceL + o);
      short8 wchh = *(const short8*)(WchH + o);
      short8 wchl = *(const short8*)(WchL + o);
      short8 whh_h = *(const short8*)(whhH + o);
      short8 whh_l = *(const short8*)(whhL + o);
      gi[ct] = __builtin_amdgcn_mfma_f32_16x16x32_bf16(EsH[kk], wceh, gi[ct], 0,0,0);
      gi[ct] = __builtin_amdgcn_mfma_f32_16x16x32_bf16(EsL[kk], wceh, gi[ct], 0,0,0);
      gi[ct] = __builtin_amdgcn_mfma_f32_16x16x32_bf16(EsH[kk], wcel, gi[ct], 0,0,0);
      gi[ct] = __builtin_amdgcn_mfma_f32_16x16x32_bf16(GHf[kk], wchh, gi[ct], 0,0,0);
      gi[ct] = __builtin_amdgcn_mfma_f32_16x16x32_bf16(GLf[kk], wchh, gi[ct], 0,0,0);
      gi[ct] = __builtin_amdgcn_mfma_f32_16x16x32_bf16(GHf[kk], wchl, gi[ct], 0,0,0);
      gh[ct] = __builtin_amdgcn_mfma_f32_16x16x32_bf16(HH[kk], whh_h, gh[ct], 0,0,0);
      gh[ct] = __builtin_amdgcn_mfma_f32_16x16x32_bf16(HL[kk], whh_h, gh[ct], 0,0,0);
      gh[ct] = __builtin_amdgcn_mfma_f32_16x16x32_bf16(HH[kk], whh_l, gh[ct], 0,0,0);
    }
  }

#pragma unroll
  for (int ct = 0; ct < 4; ++ct)
#pragma unroll
    for (int i = 0; i < 4; ++i) {
      int n = row0 + i;
      if (n < nNodes) {
        int jh = ct*16 + lr;
        float r = 1.f/(1.f + expf(-(gi[ct][i] + gh[ct][i])));
        float z = 1.f/(1.f + expf(-(gi[ct+4][i] + gh[ct+4][i])));
        float nn = tanhf(gi[ct+8][i] + r * gh[ct+8][i]);
        float hv = h_old[(size_t)n*64 + jh];
        float hn = (1.f - z)*nn + z*hv;
        h_new[(size_t)n*64 + jh] = hn;
        h_newb[(size_t)n*64 + jh] = (unsigned short)f2bf(hn);
      }
    }
}

__global__ __launch_bounds__(256) void out_mlp(
    const float* __restrict__ h, const int* __restrict__ pm,
    const float* __restrict__ W1, const float* __restrict__ b1,
    const float* __restrict__ W2, const float* __restrict__ b2,
    float* __restrict__ out, int nPosts) {
  int tid = threadIdx.x;
  int lane = tid & 63;
  int p = blockIdx.x*4 + (tid >> 6);
  if (p >= nPosts) return;
  int n = pm[p];
  float v = h[(size_t)n*64 + lane];
  int row = lane & 31;
  float o = b1[row];
#pragma unroll
  for (int k = 0; k < 64; ++k) {
    float vb = __shfl(v, k);
    o += vb * W1[row*64 + k];
  }
  o = fmaxf(o, 0.f);
  float val = o * W2[row] * 0.5f;  // each row computed twice -> halve
#pragma unroll
  for (int offm = 32; offm > 0; offm >>= 1) val += __shfl_xor(val, offm);
  if (lane == 0) out[p] = 1.f/(1.f + expf(-(val + b2[0])));
}

static inline char* aln(char*& w, size_t bytes) {
  uintptr_t p = ((uintptr_t)w + 255) & ~(uintptr_t)255;
  char* r = (char*)p;
  w = r + bytes;
  return r;
}

extern "C" void kernel_launch(void* const* d_in, const int* in_sizes, int n_in,
                              void* d_out, int out_size, void* d_ws, size_t ws_size,
                              hipStream_t stream) {
  const float* X    = (const float*)d_in[0];
  const float* EA   = (const float*)d_in[1];
  const int*   EI   = (const int*)d_in[2];
  const int*   PM   = (const int*)d_in[3];
  const float* Wn   = (const float*)d_in[5];
  const float* bn   = (const float*)d_in[6];
  const float* We   = (const float*)d_in[7];
  const float* be   = (const float*)d_in[8];
  const float* Wagg = (const float*)d_in[9];
  const float* bagg = (const float*)d_in[10];
  const float* wih  = (const float*)d_in[11];
  const float* whh  = (const float*)d_in[12];
  const float* bih  = (const float*)d_in[13];
  const float* bhh  = (const float*)d_in[14];
  const float* W1   = (const float*)d_in[15];
  const float* b1   = (const float*)d_in[16];
  const float* W2   = (const float*)d_in[17];
  const float* b2   = (const float*)d_in[18];
  float* out = (float*)d_out;

  int nNodes = in_sizes[0] / 128;
  int nEdges = in_sizes[1] / 64;
  int nPosts = in_sizes[3];
  const int* src = EI;
  const int* dst = EI + nEdges;
  int nSB = (nNodes + 4095) / 4096;

  char* w = (char*)d_ws;
  float* h0   = (float*)aln(w, (size_t)nNodes * 64 * 4);
  float* h1   = (float*)aln(w, (size_t)nNodes * 64 * 4);
  unsigned short* h0b = (unsigned short*)aln(w, (size_t)nNodes * 64 * 2);
  unsigned short* h1b = (unsigned short*)aln(w, (size_t)nNodes * 64 * 2);
  float* Esum = (float*)aln(w, (size_t)nNodes * 64 * 4);
  float* G    = (float*)aln(w, (size_t)nNodes * 64 * 4);
  short* WceH = (short*)aln(w, 12288 * 2);
  short* WceL = (short*)aln(w, 12288 * 2);
  short* WchH = (short*)aln(w, 12288 * 2);
  short* WchL = (short*)aln(w, 12288 * 2);
  short* whhH = (short*)aln(w, 12288 * 2);
  short* whhL = (short*)aln(w, 12288 * 2);
  float* bihA = (float*)aln(w, 192 * 4);
  int*   off  = (int*)aln(w, (size_t)(nNodes + 1) * 4);
  int*   deg  = (int*)aln(w, (size_t)nNodes * 4);
  int*   cur  = (int*)aln(w, (size_t)nNodes * 4);
  int*   srcs = (int*)aln(w, (size_t)nEdges * 4);
  int*   bsum = (int*)aln(w, (size_t)nSB * 4);
  int*   boff = (int*)aln(w, (size_t)nSB * 4);
  unsigned short* encb = (unsigned short*)aln(w, (size_t)nEdges * 64 * 2);

  hipMemsetAsync(deg, 0, (size_t)nNodes * 4, stream);
  hipMemsetAsync(cur, 0, (size_t)nNodes * 4, stream);

  hist_deg<<<2048, 256, 0, stream>>>(dst, deg, nEdges);
  scan_pass1<<<nSB, 256, 0, stream>>>(deg, bsum, nNodes);
  scan_pass2<<<1, 1, 0, stream>>>(bsum, boff, off, nSB, nNodes);
  scan_pass3<<<nSB, 256, 0, stream>>>(deg, boff, off, nNodes);

  node_encode<<<(nNodes + 63) / 64, 256, 0, stream>>>(X, Wn, bn, h0, h0b, nNodes);
  edge_mlp<<<(nEdges + 127) / 128, 256, 0, stream>>>(EA, We, be, src, dst, off, cur,
                                                     srcs, encb, nEdges);
  seg_sum<<<(nNodes + 15) / 16, 256, 0, stream>>>(encb, off, Esum, nNodes);
  make_combos<<<48, 256, 0, stream>>>(wih, Wagg, bagg, whh,
                                      WceH, WceL, WchH, WchL, whhH, whhL, bihA);

  // layer 1
  gather_G<<<(nNodes + 15) / 16, 256, 0, stream>>>(h0b, off, srcs, G, nNodes);
  layer_dense<<<(nNodes + 63) / 64, 256, 0, stream>>>(
      h0, Esum, G, deg, WceH, WceL, WchH, WchL, whhH, whhL,
      bihA, bih, bhh, h1, h1b, nNodes);
  // layer 2
  gather_G<<<(nNodes + 15) / 16, 256, 0, stream>>>(h1b, off, srcs, G, nNodes);
  layer_dense<<<(nNodes + 63) / 64, 256, 0, stream>>>(
      h1, Esum, G, deg, WceH, WceL, WchH, WchL, whhH, whhL,
      bihA, bih, bhh, h0, h0b, nNodes);

  out_mlp<<<(nPosts + 3) / 4, 256, 0, stream>>>(h0, PM, W1, b1, W2, b2, out, nPosts);
}

// Round 11
// 769.977 us; speedup vs baseline: 1.2192x; 1.0155x over previous
//
#include <hip/hip_runtime.h>

using short8  = __attribute__((ext_vector_type(8))) short;
using ushort8 = __attribute__((ext_vector_type(8))) unsigned short;
using us4     = __attribute__((ext_vector_type(4))) unsigned short;
using f32x4   = __attribute__((ext_vector_type(4))) float;

static __device__ __forceinline__ short f2bf(float f) {
  unsigned u = __float_as_uint(f);
  u += 0x7fffu + ((u >> 16) & 1u);   // RNE to bf16
  return (short)(u >> 16);
}
static __device__ __forceinline__ float bf2f(short s) {
  return __uint_as_float(((unsigned)(unsigned short)s) << 16);
}
static __device__ __forceinline__ float us2f(unsigned short s) {
  return __uint_as_float(((unsigned)s) << 16);
}
static __device__ __forceinline__ short8 load8_bf16(const float* __restrict__ p) {
  const f32x4* q = (const f32x4*)p;
  f32x4 a = q[0], b = q[1];
  short8 r;
  r[0]=f2bf(a[0]); r[1]=f2bf(a[1]); r[2]=f2bf(a[2]); r[3]=f2bf(a[3]);
  r[4]=f2bf(b[0]); r[5]=f2bf(b[1]); r[6]=f2bf(b[2]); r[7]=f2bf(b[3]);
  return r;
}
// hi/lo bf16 split: v ~= hi + lo
static __device__ __forceinline__ void split8(const float* p, short8& hi, short8& lo) {
  const f32x4* q = (const f32x4*)p;
  f32x4 a = q[0], b = q[1];
  float v[8] = {a[0],a[1],a[2],a[3],b[0],b[1],b[2],b[3]};
#pragma unroll
  for (int j = 0; j < 8; ++j) {
    short h = f2bf(v[j]);
    hi[j] = h;
    lo[j] = f2bf(v[j] - bf2f(h));
  }
}

// ---------------- node encoder: h = relu(X @ Wn^T + bn), MFMA, A-split ----------------
__global__ __launch_bounds__(256) void node_encode(
    const float* __restrict__ X, const float* __restrict__ Wn,
    const float* __restrict__ bn, float* __restrict__ h,
    unsigned short* __restrict__ hb, int nNodes) {
  int tid = threadIdx.x, lane = tid & 63, w = tid >> 6, lg = lane >> 4, lr = lane & 15;
  short8 bf[4][4];
#pragma unroll
  for (int t = 0; t < 4; ++t)
#pragma unroll
    for (int kk = 0; kk < 4; ++kk)
      bf[t][kk] = load8_bf16(Wn + (t*16+lr)*128 + kk*32 + lg*8);
  float bias[4];
#pragma unroll
  for (int t = 0; t < 4; ++t) bias[t] = bn[t*16+lr];

  int base = blockIdx.x * 64 + w * 16;
  int arow = base + lr;
  int nn = arow < nNodes ? arow : nNodes - 1;
  f32x4 acc[4] = {};
#pragma unroll
  for (int kk = 0; kk < 4; ++kk) {
    short8 aH, aL;
    split8(X + (size_t)nn*128 + kk*32 + lg*8, aH, aL);
#pragma unroll
    for (int t = 0; t < 4; ++t) {
      acc[t] = __builtin_amdgcn_mfma_f32_16x16x32_bf16(aH, bf[t][kk], acc[t], 0, 0, 0);
      acc[t] = __builtin_amdgcn_mfma_f32_16x16x32_bf16(aL, bf[t][kk], acc[t], 0, 0, 0);
    }
  }
#pragma unroll
  for (int t = 0; t < 4; ++t)
#pragma unroll
    for (int i = 0; i < 4; ++i) {
      int orow = base + lg*4 + i;
      if (orow < nNodes) {
        float v = fmaxf(acc[t][i] + bias[t], 0.f);
        h[(size_t)orow*64 + t*16 + lr] = v;
        hb[(size_t)orow*64 + t*16 + lr] = (unsigned short)f2bf(v);
      }
    }
}

// ---------------- CSR build ----------------
__global__ __launch_bounds__(256) void hist_deg(
    const int* __restrict__ dst, int* __restrict__ deg, int nEdges) {
  for (int e = blockIdx.x*256 + threadIdx.x; e < nEdges; e += gridDim.x*256)
    atomicAdd(&deg[dst[e]], 1);
}

__global__ __launch_bounds__(256) void scan_pass1(
    const int* __restrict__ deg, int* __restrict__ bsum, int n) {
  int b = blockIdx.x, tid = threadIdx.x;
  int base = b * 4096;
  int s = 0;
  for (int j = tid; j < 4096; j += 256) {
    int i = base + j;
    s += (i < n) ? deg[i] : 0;
  }
  __shared__ int ws[4];
#pragma unroll
  for (int o = 32; o; o >>= 1) s += __shfl_down(s, o);
  if ((tid & 63) == 0) ws[tid >> 6] = s;
  __syncthreads();
  if (tid == 0) bsum[b] = ws[0] + ws[1] + ws[2] + ws[3];
}

// pass3 with fused block-prefix (was pass2): each block sums bsum[0..b-1] itself
__global__ __launch_bounds__(256) void scan_pass3(
    const int* __restrict__ deg, const int* __restrict__ bsum,
    int* __restrict__ off, int n, int nBlocks) {
  int b = blockIdx.x, tid = threadIdx.x;
  int lane = tid & 63, w = tid >> 6;
  __shared__ int bpre_s;
  if (tid == 0) {
    int run = 0;
    for (int k = 0; k < b; ++k) run += bsum[k];
    bpre_s = run;
    if (b == nBlocks - 1) off[n] = run + bsum[b];
  }
  int base = b * 4096 + tid * 16;
  int d[16], tot = 0;
#pragma unroll
  for (int j = 0; j < 16; ++j) {
    d[j] = (base + j < n) ? deg[base + j] : 0;
    tot += d[j];
  }
  int s = tot;
#pragma unroll
  for (int o = 1; o < 64; o <<= 1) {
    int t = __shfl_up(s, o);
    if (lane >= o) s += t;
  }
  __shared__ int ws[4];
  if (lane == 63) ws[w] = s;
  __syncthreads();
  int wo = 0;
  for (int k = 0; k < 4; ++k) wo += (k < w) ? ws[k] : 0;
  int run = bpre_s + wo + s - tot;
#pragma unroll
  for (int j = 0; j < 16; ++j) {
    if (base + j < n) off[base + j] = run;
    run += d[j];
  }
}

// ---------------- edge MLP: stream EA, MFMA, fused CSR-fill, permuted bf16 enc store ----
__global__ __launch_bounds__(256) void edge_mlp(
    const float* __restrict__ EA, const float* __restrict__ We,
    const float* __restrict__ be, const int* __restrict__ src,
    const int* __restrict__ dst, const int* __restrict__ off,
    int* __restrict__ cur, int* __restrict__ srcs,
    unsigned short* __restrict__ encb, int nEdges) {
  int tid = threadIdx.x, lane = tid & 63, w = tid >> 6;
  int lr = lane & 15, lg = lane >> 4;

  short8 bf[4][2];
#pragma unroll
  for (int t = 0; t < 4; ++t)
#pragma unroll
    for (int kk = 0; kk < 2; ++kk)
      bf[t][kk] = load8_bf16(We + (t*16+lr)*64 + kk*32 + lg*8);
  float bias[4];
#pragma unroll
  for (int t = 0; t < 4; ++t) bias[t] = be[t*16+lr];

  int e0 = blockIdx.x * 128 + w * 32;   // this wave's 32 edges
  int pos_reg = 0;
  if (lane < 32) {
    int e = e0 + lane;
    if (e < nEdges) {
      int d = dst[e];
      pos_reg = off[d] + atomicAdd(&cur[d], 1);
      srcs[pos_reg] = src[e];
    }
  }

  int c0 = e0 + lr;      if (c0 >= nEdges) c0 = nEdges - 1;
  int c1 = e0 + 16 + lr; if (c1 >= nEdges) c1 = nEdges - 1;
  const float* p0 = EA + (size_t)c0 * 64;
  const float* p1 = EA + (size_t)c1 * 64;
  f32x4 acc[2][4] = {};
#pragma unroll
  for (int kk = 0; kk < 2; ++kk) {
    short8 a0 = load8_bf16(p0 + kk*32 + lg*8);
    short8 a1 = load8_bf16(p1 + kk*32 + lg*8);
#pragma unroll
    for (int t = 0; t < 4; ++t) {
      acc[0][t] = __builtin_amdgcn_mfma_f32_16x16x32_bf16(a0, bf[t][kk], acc[0][t], 0,0,0);
      acc[1][t] = __builtin_amdgcn_mfma_f32_16x16x32_bf16(a1, bf[t][kk], acc[1][t], 0,0,0);
    }
  }
#pragma unroll
  for (int b = 0; b < 2; ++b)
#pragma unroll
    for (int i = 0; i < 4; ++i) {
      int rloc = b*16 + lg*4 + i;
      int e = e0 + rloc;
      int pos = __shfl(pos_reg, rloc);
      if (e < nEdges) {
        us4 v;
#pragma unroll
        for (int t = 0; t < 4; ++t)
          v[t] = (unsigned short)f2bf(fmaxf(acc[b][t][i] + bias[t], 0.f));
        *(us4*)(encb + (size_t)pos*64 + lr*4) = v;
      }
    }
}

// ---------------- fused seg_sum + layer-1 h-gather (lean: 2 nodes/wave) ----------------
// Esum[n] = sum of contiguous encb rows (permuted features);
// G[n]    = sum of hb[srcs[...]] rows (natural features).
__global__ __launch_bounds__(256) void seg_gather(
    const unsigned short* __restrict__ encb, const unsigned short* __restrict__ hb,
    const int* __restrict__ off, const int* __restrict__ srcs,
    float* __restrict__ Esum, float* __restrict__ G, int nNodes) {
  int tid = threadIdx.x, lane = tid & 63, w = tid >> 6;
  int er = lane >> 3, fs = lane & 7;
  int n0 = (blockIdx.x * 4 + w) * 2;
  if (n0 >= nNodes) return;
  int a[2], b[2];
#pragma unroll
  for (int j = 0; j < 2; ++j) {
    int n = n0 + j;
    a[j] = (n < nNodes) ? off[n] : 0;
    b[j] = (n < nNodes) ? off[n + 1] : 0;
  }
  float ae[2][8], ag[2][8];
#pragma unroll
  for (int j = 0; j < 2; ++j)
#pragma unroll
    for (int q = 0; q < 8; ++q) { ae[j][q] = 0.f; ag[j][q] = 0.f; }
  int mx = b[0] - a[0];
  if (b[1] - a[1] > mx) mx = b[1] - a[1];

  int s0[2], s1[2];
#pragma unroll
  for (int j = 0; j < 2; ++j) {
    int i0 = a[j] + er, i1 = i0 + 8;
    int c0 = (i0 < b[j]) ? i0 : 0;
    int c1 = (i1 < b[j]) ? i1 : 0;
    bool any = b[j] > a[j];
    s0[j] = any ? srcs[c0] : 0;
    s1[j] = any ? srcs[c1] : 0;
  }
  for (int t = 0; t < mx; t += 16) {
    ushort8 ev0[2], ev1[2], gv0[2], gv1[2];
#pragma unroll
    for (int j = 0; j < 2; ++j) {
      int i0 = a[j] + t + er, i1 = i0 + 8;
      int c0 = (i0 < b[j]) ? i0 : 0;
      int c1 = (i1 < b[j]) ? i1 : 0;
      ev0[j] = *(const ushort8*)(encb + (size_t)c0 * 64 + fs * 8);
      ev1[j] = *(const ushort8*)(encb + (size_t)c1 * 64 + fs * 8);
      gv0[j] = *(const ushort8*)(hb + (size_t)s0[j] * 64 + fs * 8);
      gv1[j] = *(const ushort8*)(hb + (size_t)s1[j] * 64 + fs * 8);
    }
    // prefetch next srcs while loads are in flight
    int p0[2], p1[2];
    if (t + 16 < mx) {
#pragma unroll
      for (int j = 0; j < 2; ++j) {
        int i0 = a[j] + t + 16 + er, i1 = i0 + 8;
        int c0 = (i0 < b[j]) ? i0 : 0;
        int c1 = (i1 < b[j]) ? i1 : 0;
        bool any = b[j] > a[j];
        p0[j] = any ? srcs[c0] : 0;
        p1[j] = any ? srcs[c1] : 0;
      }
    } else {
#pragma unroll
      for (int j = 0; j < 2; ++j) { p0[j] = 0; p1[j] = 0; }
    }
#pragma unroll
    for (int j = 0; j < 2; ++j) {
      int i0 = a[j] + t + er, i1 = i0 + 8;
      if (i0 < b[j]) {
#pragma unroll
        for (int q = 0; q < 8; ++q) {
          ae[j][q] += us2f(ev0[j][q]);
          ag[j][q] += us2f(gv0[j][q]);
        }
      }
      if (i1 < b[j]) {
#pragma unroll
        for (int q = 0; q < 8; ++q) {
          ae[j][q] += us2f(ev1[j][q]);
          ag[j][q] += us2f(gv1[j][q]);
        }
      }
    }
#pragma unroll
    for (int j = 0; j < 2; ++j) { s0[j] = p0[j]; s1[j] = p1[j]; }
  }
#pragma unroll
  for (int j = 0; j < 2; ++j)
#pragma unroll
    for (int q = 0; q < 8; ++q) {
      float v = ae[j][q];
      v += __shfl_xor(v, 8); v += __shfl_xor(v, 16); v += __shfl_xor(v, 32);
      ae[j][q] = v;
      float u = ag[j][q];
      u += __shfl_xor(u, 8); u += __shfl_xor(u, 16); u += __shfl_xor(u, 32);
      ag[j][q] = u;
    }
  if (er == 0) {
#pragma unroll
    for (int j = 0; j < 2; ++j) {
      int n = n0 + j;
      if (n < nNodes) {
        f32x4 elo = {ae[j][0], ae[j][1], ae[j][2], ae[j][3]};
        f32x4 ehi = {ae[j][4], ae[j][5], ae[j][6], ae[j][7]};
        *(f32x4*)(Esum + (size_t)n * 64 + fs * 8) = elo;
        *(f32x4*)(Esum + (size_t)n * 64 + fs * 8 + 4) = ehi;
        f32x4 glo = {ag[j][0], ag[j][1], ag[j][2], ag[j][3]};
        f32x4 ghi = {ag[j][4], ag[j][5], ag[j][6], ag[j][7]};
        *(f32x4*)(G + (size_t)n * 64 + fs * 8) = glo;
        *(f32x4*)(G + (size_t)n * 64 + fs * 8 + 4) = ghi;
      }
    }
  }
}

// ---------------- weight combos (hi/lo bf16 splits; Wce k-rows permuted) ----------------
__global__ __launch_bounds__(256) void make_combos(
    const float* __restrict__ wih, const float* __restrict__ Wagg,
    const float* __restrict__ bagg, const float* __restrict__ whh,
    short* __restrict__ WceH, short* __restrict__ WceL,
    short* __restrict__ WchH, short* __restrict__ WchL,
    short* __restrict__ whhH, short* __restrict__ whhL, float* __restrict__ bihA) {
  int idx = blockIdx.x*256 + threadIdx.x;
  if (idx < 12288) {
    int r = idx >> 6, k = idx & 63;
    float a = 0.f, b = 0.f;
    for (int j = 0; j < 64; ++j) {
      float ww = wih[r*64 + j];
      a += ww * Wagg[j*128 + k];
      b += ww * Wagg[j*128 + 64 + k];
    }
    short ah = f2bf(a);
    WchH[idx] = ah; WchL[idx] = f2bf(a - bf2f(ah));
    int kp = (k & 15) * 4 + (k >> 4);
    short bh = f2bf(b);
    WceH[r*64 + kp] = bh; WceL[r*64 + kp] = f2bf(b - bf2f(bh));
    float wv = whh[idx];
    short hh = f2bf(wv);
    whhH[idx] = hh; whhL[idx] = f2bf(wv - bf2f(hh));
    if (idx < 192) {
      float s = 0.f;
      for (int j = 0; j < 64; ++j) s += wih[idx*64 + j] * bagg[j];
      bihA[idx] = s;
    }
  }
}

// ---------------- h gather (layer 2): software-pipelined ----------------
__global__ __launch_bounds__(256) void gather_G(
    const unsigned short* __restrict__ hb, const int* __restrict__ off,
    const int* __restrict__ srcs, float* __restrict__ G, int nNodes) {
  int tid = threadIdx.x, lane = tid & 63, w = tid >> 6;
  int er = lane >> 3, fs = lane & 7;
  int n0 = (blockIdx.x * 4 + w) * 4;
  if (n0 >= nNodes) return;
  int a[4], b[4];
#pragma unroll
  for (int j = 0; j < 4; ++j) {
    int n = n0 + j;
    a[j] = (n < nNodes) ? off[n] : 0;
    b[j] = (n < nNodes) ? off[n + 1] : 0;
  }
  float acc[4][8];
#pragma unroll
  for (int j = 0; j < 4; ++j)
#pragma unroll
    for (int q = 0; q < 8; ++q) acc[j][q] = 0.f;
  int mx = 0;
#pragma unroll
  for (int j = 0; j < 4; ++j) { int c = b[j] - a[j]; if (c > mx) mx = c; }

  int s0[4], s1[4];
#pragma unroll
  for (int j = 0; j < 4; ++j) {
    int i0 = a[j] + er, i1 = i0 + 8;
    int c0 = (i0 < b[j]) ? i0 : 0;
    int c1 = (i1 < b[j]) ? i1 : 0;
    bool any = b[j] > a[j];
    s0[j] = any ? srcs[c0] : 0;
    s1[j] = any ? srcs[c1] : 0;
  }
  for (int t = 0; t < mx; t += 16) {
    ushort8 v0[4], v1[4];
#pragma unroll
    for (int j = 0; j < 4; ++j) {
      v0[j] = *(const ushort8*)(hb + (size_t)s0[j] * 64 + fs * 8);
      v1[j] = *(const ushort8*)(hb + (size_t)s1[j] * 64 + fs * 8);
    }
    int p0[4], p1[4];
    if (t + 16 < mx) {
#pragma unroll
      for (int j = 0; j < 4; ++j) {
        int i0 = a[j] + t + 16 + er, i1 = i0 + 8;
        int c0 = (i0 < b[j]) ? i0 : 0;
        int c1 = (i1 < b[j]) ? i1 : 0;
        bool any = b[j] > a[j];
        p0[j] = any ? srcs[c0] : 0;
        p1[j] = any ? srcs[c1] : 0;
      }
    } else {
#pragma unroll
      for (int j = 0; j < 4; ++j) { p0[j] = 0; p1[j] = 0; }
    }
#pragma unroll
    for (int j = 0; j < 4; ++j) {
      int i0 = a[j] + t + er, i1 = i0 + 8;
      if (i0 < b[j]) {
#pragma unroll
        for (int q = 0; q < 8; ++q) acc[j][q] += us2f(v0[j][q]);
      }
      if (i1 < b[j]) {
#pragma unroll
        for (int q = 0; q < 8; ++q) acc[j][q] += us2f(v1[j][q]);
      }
    }
#pragma unroll
    for (int j = 0; j < 4; ++j) { s0[j] = p0[j]; s1[j] = p1[j]; }
  }
#pragma unroll
  for (int j = 0; j < 4; ++j)
#pragma unroll
    for (int q = 0; q < 8; ++q) {
      float v = acc[j][q];
      v += __shfl_xor(v, 8);
      v += __shfl_xor(v, 16);
      v += __shfl_xor(v, 32);
      acc[j][q] = v;
    }
  if (er == 0) {
#pragma unroll
    for (int j = 0; j < 4; ++j) {
      int n = n0 + j;
      if (n < nNodes) {
        f32x4 lo = {acc[j][0], acc[j][1], acc[j][2], acc[j][3]};
        f32x4 hi = {acc[j][4], acc[j][5], acc[j][6], acc[j][7]};
        *(f32x4*)(G + (size_t)n * 64 + fs * 8) = lo;
        *(f32x4*)(G + (size_t)n * 64 + fs * 8 + 4) = hi;
      }
    }
  }
}

// ---------------- dense layer: MFMA (gi & gh) + GRU, fully streaming ----------------
__global__ __launch_bounds__(256) void layer_dense(
    const float* __restrict__ h_old, const float* __restrict__ Esum,
    const float* __restrict__ G, const int* __restrict__ deg,
    const short* __restrict__ WceH, const short* __restrict__ WceL,
    const short* __restrict__ WchH, const short* __restrict__ WchL,
    const short* __restrict__ whhH, const short* __restrict__ whhL,
    const float* __restrict__ bihA, const float* __restrict__ bih,
    const float* __restrict__ bhh, float* __restrict__ h_new,
    unsigned short* __restrict__ h_newb, int nNodes) {
  int tid = threadIdx.x, lane = tid & 63, w = tid >> 6;
  int lr = lane & 15, lg = lane >> 4;
  int nb = blockIdx.x * 64;

  int arow = nb + w*16 + lr; if (arow >= nNodes) arow = nNodes - 1;
  short8 EsH[2], EsL[2], GHf[2], GLf[2], HH[2], HL[2];
#pragma unroll
  for (int kk = 0; kk < 2; ++kk) {
    split8(Esum + (size_t)arow*64 + kk*32 + lg*8, EsH[kk], EsL[kk]);
    split8(G + (size_t)arow*64 + kk*32 + lg*8, GHf[kk], GLf[kk]);
    split8(h_old + (size_t)arow*64 + kk*32 + lg*8, HH[kk], HL[kk]);
  }

  int row0 = nb + w*16 + lg*4;
  float degv[4];
#pragma unroll
  for (int i = 0; i < 4; ++i) {
    int n = row0 + i;
    degv[i] = (n < nNodes) ? (float)deg[n] : 0.f;
  }

  f32x4 gi[12], gh[12];
#pragma unroll
  for (int ct = 0; ct < 12; ++ct) {
    float bi = bih[ct*16 + lr], ba = bihA[ct*16 + lr], bh = bhh[ct*16 + lr];
#pragma unroll
    for (int i = 0; i < 4; ++i) { gi[ct][i] = bi + degv[i]*ba; gh[ct][i] = bh; }
  }

#pragma unroll
  for (int ct = 0; ct < 12; ++ct) {
    int wb = (ct*16 + lr)*64 + lg*8;
#pragma unroll
    for (int kk = 0; kk < 2; ++kk) {
      int o = wb + kk*32;
      short8 wceh = *(const short8*)(WceH + o);
      short8 wcel = *(const short8*)(WceL + o);
      short8 wchh = *(const short8*)(WchH + o);
      short8 wchl = *(const short8*)(WchL + o);
      short8 whh_h = *(const short8*)(whhH + o);
      short8 whh_l = *(const short8*)(whhL + o);
      gi[ct] = __builtin_amdgcn_mfma_f32_16x16x32_bf16(EsH[kk], wceh, gi[ct], 0,0,0);
      gi[ct] = __builtin_amdgcn_mfma_f32_16x16x32_bf16(EsL[kk], wceh, gi[ct], 0,0,0);
      gi[ct] = __builtin_amdgcn_mfma_f32_16x16x32_bf16(EsH[kk], wcel, gi[ct], 0,0,0);
      gi[ct] = __builtin_amdgcn_mfma_f32_16x16x32_bf16(GHf[kk], wchh, gi[ct], 0,0,0);
      gi[ct] = __builtin_amdgcn_mfma_f32_16x16x32_bf16(GLf[kk], wchh, gi[ct], 0,0,0);
      gi[ct] = __builtin_amdgcn_mfma_f32_16x16x32_bf16(GHf[kk], wchl, gi[ct], 0,0,0);
      gh[ct] = __builtin_amdgcn_mfma_f32_16x16x32_bf16(HH[kk], whh_h, gh[ct], 0,0,0);
      gh[ct] = __builtin_amdgcn_mfma_f32_16x16x32_bf16(HL[kk], whh_h, gh[ct], 0,0,0);
      gh[ct] = __builtin_amdgcn_mfma_f32_16x16x32_bf16(HH[kk], whh_l, gh[ct], 0,0,0);
    }
  }

#pragma unroll
  for (int ct = 0; ct < 4; ++ct)
#pragma unroll
    for (int i = 0; i < 4; ++i) {
      int n = row0 + i;
      if (n < nNodes) {
        int jh = ct*16 + lr;
        float r = 1.f/(1.f + expf(-(gi[ct][i] + gh[ct][i])));
        float z = 1.f/(1.f + expf(-(gi[ct+4][i] + gh[ct+4][i])));
        float nn = tanhf(gi[ct+8][i] + r * gh[ct+8][i]);
        float hv = h_old[(size_t)n*64 + jh];
        float hn = (1.f - z)*nn + z*hv;
        h_new[(size_t)n*64 + jh] = hn;
        h_newb[(size_t)n*64 + jh] = (unsigned short)f2bf(hn);
      }
    }
}

__global__ __launch_bounds__(256) void out_mlp(
    const float* __restrict__ h, const int* __restrict__ pm,
    const float* __restrict__ W1, const float* __restrict__ b1,
    const float* __restrict__ W2, const float* __restrict__ b2,
    float* __restrict__ out, int nPosts) {
  int tid = threadIdx.x;
  int lane = tid & 63;
  int p = blockIdx.x*4 + (tid >> 6);
  if (p >= nPosts) return;
  int n = pm[p];
  float v = h[(size_t)n*64 + lane];
  int row = lane & 31;
  float o = b1[row];
#pragma unroll
  for (int k = 0; k < 64; ++k) {
    float vb = __shfl(v, k);
    o += vb * W1[row*64 + k];
  }
  o = fmaxf(o, 0.f);
  float val = o * W2[row] * 0.5f;  // each row computed twice -> halve
#pragma unroll
  for (int offm = 32; offm > 0; offm >>= 1) val += __shfl_xor(val, offm);
  if (lane == 0) out[p] = 1.f/(1.f + expf(-(val + b2[0])));
}

static inline char* aln(char*& w, size_t bytes) {
  uintptr_t p = ((uintptr_t)w + 255) & ~(uintptr_t)255;
  char* r = (char*)p;
  w = r + bytes;
  return r;
}

extern "C" void kernel_launch(void* const* d_in, const int* in_sizes, int n_in,
                              void* d_out, int out_size, void* d_ws, size_t ws_size,
                              hipStream_t stream) {
  const float* X    = (const float*)d_in[0];
  const float* EA   = (const float*)d_in[1];
  const int*   EI   = (const int*)d_in[2];
  const int*   PM   = (const int*)d_in[3];
  const float* Wn   = (const float*)d_in[5];
  const float* bn   = (const float*)d_in[6];
  const float* We   = (const float*)d_in[7];
  const float* be   = (const float*)d_in[8];
  const float* Wagg = (const float*)d_in[9];
  const float* bagg = (const float*)d_in[10];
  const float* wih  = (const float*)d_in[11];
  const float* whh  = (const float*)d_in[12];
  const float* bih  = (const float*)d_in[13];
  const float* bhh  = (const float*)d_in[14];
  const float* W1   = (const float*)d_in[15];
  const float* b1   = (const float*)d_in[16];
  const float* W2   = (const float*)d_in[17];
  const float* b2   = (const float*)d_in[18];
  float* out = (float*)d_out;

  int nNodes = in_sizes[0] / 128;
  int nEdges = in_sizes[1] / 64;
  int nPosts = in_sizes[3];
  const int* src = EI;
  const int* dst = EI + nEdges;
  int nSB = (nNodes + 4095) / 4096;

  char* w = (char*)d_ws;
  float* h0   = (float*)aln(w, (size_t)nNodes * 64 * 4);
  float* h1   = (float*)aln(w, (size_t)nNodes * 64 * 4);
  unsigned short* h0b = (unsigned short*)aln(w, (size_t)nNodes * 64 * 2);
  unsigned short* h1b = (unsigned short*)aln(w, (size_t)nNodes * 64 * 2);
  float* Esum = (float*)aln(w, (size_t)nNodes * 64 * 4);
  float* G    = (float*)aln(w, (size_t)nNodes * 64 * 4);
  short* WceH = (short*)aln(w, 12288 * 2);
  short* WceL = (short*)aln(w, 12288 * 2);
  short* WchH = (short*)aln(w, 12288 * 2);
  short* WchL = (short*)aln(w, 12288 * 2);
  short* whhH = (short*)aln(w, 12288 * 2);
  short* whhL = (short*)aln(w, 12288 * 2);
  float* bihA = (float*)aln(w, 192 * 4);
  int*   off  = (int*)aln(w, (size_t)(nNodes + 1) * 4);
  int*   deg  = (int*)aln(w, (size_t)nNodes * 4);
  int*   cur  = (int*)aln(w, (size_t)nNodes * 4);
  int*   srcs = (int*)aln(w, (size_t)nEdges * 4);
  int*   bsum = (int*)aln(w, (size_t)nSB * 4);
  unsigned short* encb = (unsigned short*)aln(w, (size_t)nEdges * 64 * 2);

  hipMemsetAsync(deg, 0, (size_t)nNodes * 4, stream);
  hipMemsetAsync(cur, 0, (size_t)nNodes * 4, stream);

  hist_deg<<<2048, 256, 0, stream>>>(dst, deg, nEdges);
  scan_pass1<<<nSB, 256, 0, stream>>>(deg, bsum, nNodes);
  scan_pass3<<<nSB, 256, 0, stream>>>(deg, bsum, off, nNodes, nSB);

  node_encode<<<(nNodes + 63) / 64, 256, 0, stream>>>(X, Wn, bn, h0, h0b, nNodes);
  edge_mlp<<<(nEdges + 127) / 128, 256, 0, stream>>>(EA, We, be, src, dst, off, cur,
                                                     srcs, encb, nEdges);
  make_combos<<<48, 256, 0, stream>>>(wih, Wagg, bagg, whh,
                                      WceH, WceL, WchH, WchL, whhH, whhL, bihA);

  // layer 1: fused Esum + G
  seg_gather<<<(nNodes + 7) / 8, 256, 0, stream>>>(encb, h0b, off, srcs, Esum, G, nNodes);
  layer_dense<<<(nNodes + 63) / 64, 256, 0, stream>>>(
      h0, Esum, G, deg, WceH, WceL, WchH, WchL, whhH, whhL,
      bihA, bih, bhh, h1, h1b, nNodes);
  // layer 2
  gather_G<<<(nNodes + 15) / 16, 256, 0, stream>>>(h1b, off, srcs, G, nNodes);
  layer_dense<<<(nNodes + 63) / 64, 256, 0, stream>>>(
      h1, Esum, G, deg, WceH, WceL, WchH, WchL, whhH, whhL,
      bihA, bih, bhh, h0, h0b, nNodes);

  out_mlp<<<(nPosts + 3) / 4, 256, 0, stream>>>(h0, PM, W1, b1, W2, b2, out, nPosts);
}

// Round 12
// 755.630 us; speedup vs baseline: 1.2424x; 1.0190x over previous
//
#include <hip/hip_runtime.h>

using short8  = __attribute__((ext_vector_type(8))) short;
using ushort8 = __attribute__((ext_vector_type(8))) unsigned short;
using us4     = __attribute__((ext_vector_type(4))) unsigned short;
using f32x4   = __attribute__((ext_vector_type(4))) float;

static __device__ __forceinline__ short f2bf(float f) {
  unsigned u = __float_as_uint(f);
  u += 0x7fffu + ((u >> 16) & 1u);   // RNE to bf16
  return (short)(u >> 16);
}
static __device__ __forceinline__ float bf2f(short s) {
  return __uint_as_float(((unsigned)(unsigned short)s) << 16);
}
static __device__ __forceinline__ float us2f(unsigned short s) {
  return __uint_as_float(((unsigned)s) << 16);
}
static __device__ __forceinline__ short8 load8_bf16(const float* __restrict__ p) {
  const f32x4* q = (const f32x4*)p;
  f32x4 a = q[0], b = q[1];
  short8 r;
  r[0]=f2bf(a[0]); r[1]=f2bf(a[1]); r[2]=f2bf(a[2]); r[3]=f2bf(a[3]);
  r[4]=f2bf(b[0]); r[5]=f2bf(b[1]); r[6]=f2bf(b[2]); r[7]=f2bf(b[3]);
  return r;
}
// hi/lo bf16 split: v ~= hi + lo
static __device__ __forceinline__ void split8(const float* p, short8& hi, short8& lo) {
  const f32x4* q = (const f32x4*)p;
  f32x4 a = q[0], b = q[1];
  float v[8] = {a[0],a[1],a[2],a[3],b[0],b[1],b[2],b[3]};
#pragma unroll
  for (int j = 0; j < 8; ++j) {
    short h = f2bf(v[j]);
    hi[j] = h;
    lo[j] = f2bf(v[j] - bf2f(h));
  }
}

// ---------------- node encoder: h = relu(X @ Wn^T + bn), MFMA, A-split ----------------
__global__ __launch_bounds__(256) void node_encode(
    const float* __restrict__ X, const float* __restrict__ Wn,
    const float* __restrict__ bn, float* __restrict__ h,
    unsigned short* __restrict__ hb, int nNodes) {
  int tid = threadIdx.x, lane = tid & 63, w = tid >> 6, lg = lane >> 4, lr = lane & 15;
  short8 bf[4][4];
#pragma unroll
  for (int t = 0; t < 4; ++t)
#pragma unroll
    for (int kk = 0; kk < 4; ++kk)
      bf[t][kk] = load8_bf16(Wn + (t*16+lr)*128 + kk*32 + lg*8);
  float bias[4];
#pragma unroll
  for (int t = 0; t < 4; ++t) bias[t] = bn[t*16+lr];

  int base = blockIdx.x * 64 + w * 16;
  int arow = base + lr;
  int nn = arow < nNodes ? arow : nNodes - 1;
  f32x4 acc[4] = {};
#pragma unroll
  for (int kk = 0; kk < 4; ++kk) {
    short8 aH, aL;
    split8(X + (size_t)nn*128 + kk*32 + lg*8, aH, aL);
#pragma unroll
    for (int t = 0; t < 4; ++t) {
      acc[t] = __builtin_amdgcn_mfma_f32_16x16x32_bf16(aH, bf[t][kk], acc[t], 0, 0, 0);
      acc[t] = __builtin_amdgcn_mfma_f32_16x16x32_bf16(aL, bf[t][kk], acc[t], 0, 0, 0);
    }
  }
#pragma unroll
  for (int t = 0; t < 4; ++t)
#pragma unroll
    for (int i = 0; i < 4; ++i) {
      int orow = base + lg*4 + i;
      if (orow < nNodes) {
        float v = fmaxf(acc[t][i] + bias[t], 0.f);
        h[(size_t)orow*64 + t*16 + lr] = v;
        hb[(size_t)orow*64 + t*16 + lr] = (unsigned short)f2bf(v);
      }
    }
}

// ---------------- CSR build ----------------
__global__ __launch_bounds__(256) void hist_deg(
    const int* __restrict__ dst, int* __restrict__ deg, int nEdges) {
  for (int e = blockIdx.x*256 + threadIdx.x; e < nEdges; e += gridDim.x*256)
    atomicAdd(&deg[dst[e]], 1);
}

__global__ __launch_bounds__(256) void scan_pass1(
    const int* __restrict__ deg, int* __restrict__ bsum, int n) {
  int b = blockIdx.x, tid = threadIdx.x;
  int base = b * 4096;
  int s = 0;
  for (int j = tid; j < 4096; j += 256) {
    int i = base + j;
    s += (i < n) ? deg[i] : 0;
  }
  __shared__ int ws[4];
#pragma unroll
  for (int o = 32; o; o >>= 1) s += __shfl_down(s, o);
  if ((tid & 63) == 0) ws[tid >> 6] = s;
  __syncthreads();
  if (tid == 0) bsum[b] = ws[0] + ws[1] + ws[2] + ws[3];
}

// pass3 with fused block-prefix: each block sums bsum[0..b-1] itself
__global__ __launch_bounds__(256) void scan_pass3(
    const int* __restrict__ deg, const int* __restrict__ bsum,
    int* __restrict__ off, int n, int nBlocks) {
  int b = blockIdx.x, tid = threadIdx.x;
  int lane = tid & 63, w = tid >> 6;
  __shared__ int bpre_s;
  if (tid == 0) {
    int run = 0;
    for (int k = 0; k < b; ++k) run += bsum[k];
    bpre_s = run;
    if (b == nBlocks - 1) off[n] = run + bsum[b];
  }
  int base = b * 4096 + tid * 16;
  int d[16], tot = 0;
#pragma unroll
  for (int j = 0; j < 16; ++j) {
    d[j] = (base + j < n) ? deg[base + j] : 0;
    tot += d[j];
  }
  int s = tot;
#pragma unroll
  for (int o = 1; o < 64; o <<= 1) {
    int t = __shfl_up(s, o);
    if (lane >= o) s += t;
  }
  __shared__ int ws[4];
  if (lane == 63) ws[w] = s;
  __syncthreads();
  int wo = 0;
  for (int k = 0; k < 4; ++k) wo += (k < w) ? ws[k] : 0;
  int run = bpre_s + wo + s - tot;
#pragma unroll
  for (int j = 0; j < 16; ++j) {
    if (base + j < n) off[base + j] = run;
    run += d[j];
  }
}

// ---------------- edge MLP: 64 edges/wave, stream EA, MFMA, fused CSR-fill ----
// enc feature f = t*16+c stored at position c*4+t (C-fragment layout).
__global__ __launch_bounds__(256) void edge_mlp(
    const float* __restrict__ EA, const float* __restrict__ We,
    const float* __restrict__ be, const int* __restrict__ src,
    const int* __restrict__ dst, const int* __restrict__ off,
    int* __restrict__ cur, int* __restrict__ srcs,
    unsigned short* __restrict__ encb, int nEdges) {
  int tid = threadIdx.x, lane = tid & 63, w = tid >> 6;
  int lr = lane & 15, lg = lane >> 4;

  short8 bf[4][2];
#pragma unroll
  for (int t = 0; t < 4; ++t)
#pragma unroll
    for (int kk = 0; kk < 2; ++kk)
      bf[t][kk] = load8_bf16(We + (t*16+lr)*64 + kk*32 + lg*8);
  float bias[4];
#pragma unroll
  for (int t = 0; t < 4; ++t) bias[t] = be[t*16+lr];

  int e0 = blockIdx.x * 256 + w * 64;   // this wave's 64 edges
  // fused CSR fill: each lane handles one edge (one chain per 64 edges)
  int pos_reg = 0;
  {
    int e = e0 + lane;
    if (e < nEdges) {
      int d = dst[e];
      pos_reg = off[d] + atomicAdd(&cur[d], 1);
      srcs[pos_reg] = src[e];
    }
  }

  const float* pr[4];
#pragma unroll
  for (int rb = 0; rb < 4; ++rb) {
    int c = e0 + rb*16 + lr; if (c >= nEdges) c = nEdges - 1;
    pr[rb] = EA + (size_t)c * 64;
  }
  f32x4 acc[4][4] = {};
#pragma unroll
  for (int kk = 0; kk < 2; ++kk) {
    short8 a[4];
#pragma unroll
    for (int rb = 0; rb < 4; ++rb) a[rb] = load8_bf16(pr[rb] + kk*32 + lg*8);
#pragma unroll
    for (int rb = 0; rb < 4; ++rb)
#pragma unroll
      for (int t = 0; t < 4; ++t)
        acc[rb][t] = __builtin_amdgcn_mfma_f32_16x16x32_bf16(a[rb], bf[t][kk], acc[rb][t], 0,0,0);
  }
#pragma unroll
  for (int rb = 0; rb < 4; ++rb)
#pragma unroll
    for (int i = 0; i < 4; ++i) {
      int rloc = rb*16 + lg*4 + i;
      int e = e0 + rloc;
      int pos = __shfl(pos_reg, rloc);
      if (e < nEdges) {
        us4 v;
#pragma unroll
        for (int t = 0; t < 4; ++t)
          v[t] = (unsigned short)f2bf(fmaxf(acc[rb][t][i] + bias[t], 0.f));
        *(us4*)(encb + (size_t)pos*64 + lr*4) = v;
      }
    }
}

// ---------------- fused seg_sum + layer-1 h-gather (2 nodes/wave, 4-deep) ----------------
__global__ __launch_bounds__(256) void seg_gather(
    const unsigned short* __restrict__ encb, const unsigned short* __restrict__ hb,
    const int* __restrict__ off, const int* __restrict__ srcs,
    float* __restrict__ Esum, float* __restrict__ G, int nNodes) {
  int tid = threadIdx.x, lane = tid & 63, w = tid >> 6;
  int er = lane >> 3, fs = lane & 7;
  int n0 = (blockIdx.x * 4 + w) * 2;
  if (n0 >= nNodes) return;
  int a[2], b[2];
#pragma unroll
  for (int j = 0; j < 2; ++j) {
    int n = n0 + j;
    a[j] = (n < nNodes) ? off[n] : 0;
    b[j] = (n < nNodes) ? off[n + 1] : 0;
  }
  float ae[2][8], ag[2][8];
#pragma unroll
  for (int j = 0; j < 2; ++j)
#pragma unroll
    for (int q = 0; q < 8; ++q) { ae[j][q] = 0.f; ag[j][q] = 0.f; }
  int mx = b[0] - a[0];
  if (b[1] - a[1] > mx) mx = b[1] - a[1];

  int sc[4][2];
#pragma unroll
  for (int m = 0; m < 4; ++m)
#pragma unroll
    for (int j = 0; j < 2; ++j) {
      int i = a[j] + m*8 + er;
      int c = (i < b[j]) ? i : 0;
      sc[m][j] = (b[j] > a[j]) ? srcs[c] : 0;
    }
  for (int t = 0; t < mx; t += 32) {
    ushort8 ev[4][2], gv[4][2];
#pragma unroll
    for (int m = 0; m < 4; ++m)
#pragma unroll
      for (int j = 0; j < 2; ++j) {
        int i = a[j] + t + m*8 + er;
        int c = (i < b[j]) ? i : 0;
        ev[m][j] = *(const ushort8*)(encb + (size_t)c * 64 + fs * 8);
        gv[m][j] = *(const ushort8*)(hb + (size_t)sc[m][j] * 64 + fs * 8);
      }
    int pc[4][2];
    if (t + 32 < mx) {
#pragma unroll
      for (int m = 0; m < 4; ++m)
#pragma unroll
        for (int j = 0; j < 2; ++j) {
          int i = a[j] + t + 32 + m*8 + er;
          int c = (i < b[j]) ? i : 0;
          pc[m][j] = (b[j] > a[j]) ? srcs[c] : 0;
        }
    } else {
#pragma unroll
      for (int m = 0; m < 4; ++m)
#pragma unroll
        for (int j = 0; j < 2; ++j) pc[m][j] = 0;
    }
#pragma unroll
    for (int m = 0; m < 4; ++m)
#pragma unroll
      for (int j = 0; j < 2; ++j) {
        int i = a[j] + t + m*8 + er;
        if (i < b[j]) {
#pragma unroll
          for (int q = 0; q < 8; ++q) {
            ae[j][q] += us2f(ev[m][j][q]);
            ag[j][q] += us2f(gv[m][j][q]);
          }
        }
      }
#pragma unroll
    for (int m = 0; m < 4; ++m)
#pragma unroll
      for (int j = 0; j < 2; ++j) sc[m][j] = pc[m][j];
  }
#pragma unroll
  for (int j = 0; j < 2; ++j)
#pragma unroll
    for (int q = 0; q < 8; ++q) {
      float v = ae[j][q];
      v += __shfl_xor(v, 8); v += __shfl_xor(v, 16); v += __shfl_xor(v, 32);
      ae[j][q] = v;
      float u = ag[j][q];
      u += __shfl_xor(u, 8); u += __shfl_xor(u, 16); u += __shfl_xor(u, 32);
      ag[j][q] = u;
    }
  if (er == 0) {
#pragma unroll
    for (int j = 0; j < 2; ++j) {
      int n = n0 + j;
      if (n < nNodes) {
        f32x4 elo = {ae[j][0], ae[j][1], ae[j][2], ae[j][3]};
        f32x4 ehi = {ae[j][4], ae[j][5], ae[j][6], ae[j][7]};
        *(f32x4*)(Esum + (size_t)n * 64 + fs * 8) = elo;
        *(f32x4*)(Esum + (size_t)n * 64 + fs * 8 + 4) = ehi;
        f32x4 glo = {ag[j][0], ag[j][1], ag[j][2], ag[j][3]};
        f32x4 ghi = {ag[j][4], ag[j][5], ag[j][6], ag[j][7]};
        *(f32x4*)(G + (size_t)n * 64 + fs * 8) = glo;
        *(f32x4*)(G + (size_t)n * 64 + fs * 8 + 4) = ghi;
      }
    }
  }
}

// ---------------- weight combos (hi/lo bf16 splits; Wce k-rows permuted) ----------------
__global__ __launch_bounds__(256) void make_combos(
    const float* __restrict__ wih, const float* __restrict__ Wagg,
    const float* __restrict__ bagg, const float* __restrict__ whh,
    short* __restrict__ WceH, short* __restrict__ WceL,
    short* __restrict__ WchH, short* __restrict__ WchL,
    short* __restrict__ whhH, short* __restrict__ whhL, float* __restrict__ bihA) {
  int idx = blockIdx.x*256 + threadIdx.x;
  if (idx < 12288) {
    int r = idx >> 6, k = idx & 63;
    float a = 0.f, b = 0.f;
    for (int j = 0; j < 64; ++j) {
      float ww = wih[r*64 + j];
      a += ww * Wagg[j*128 + k];
      b += ww * Wagg[j*128 + 64 + k];
    }
    short ah = f2bf(a);
    WchH[idx] = ah; WchL[idx] = f2bf(a - bf2f(ah));
    int kp = (k & 15) * 4 + (k >> 4);
    short bh = f2bf(b);
    WceH[r*64 + kp] = bh; WceL[r*64 + kp] = f2bf(b - bf2f(bh));
    float wv = whh[idx];
    short hh = f2bf(wv);
    whhH[idx] = hh; whhL[idx] = f2bf(wv - bf2f(hh));
    if (idx < 192) {
      float s = 0.f;
      for (int j = 0; j < 64; ++j) s += wih[idx*64 + j] * bagg[j];
      bihA[idx] = s;
    }
  }
}

// ---------------- h gather (layer 2): 2 nodes/wave, 4-deep pipelined ----------------
__global__ __launch_bounds__(256) void gather_G(
    const unsigned short* __restrict__ hb, const int* __restrict__ off,
    const int* __restrict__ srcs, float* __restrict__ G, int nNodes) {
  int tid = threadIdx.x, lane = tid & 63, w = tid >> 6;
  int er = lane >> 3, fs = lane & 7;
  int n0 = (blockIdx.x * 4 + w) * 2;
  if (n0 >= nNodes) return;
  int a[2], b[2];
#pragma unroll
  for (int j = 0; j < 2; ++j) {
    int n = n0 + j;
    a[j] = (n < nNodes) ? off[n] : 0;
    b[j] = (n < nNodes) ? off[n + 1] : 0;
  }
  float ag[2][8];
#pragma unroll
  for (int j = 0; j < 2; ++j)
#pragma unroll
    for (int q = 0; q < 8; ++q) ag[j][q] = 0.f;
  int mx = b[0] - a[0];
  if (b[1] - a[1] > mx) mx = b[1] - a[1];

  int sc[4][2];
#pragma unroll
  for (int m = 0; m < 4; ++m)
#pragma unroll
    for (int j = 0; j < 2; ++j) {
      int i = a[j] + m*8 + er;
      int c = (i < b[j]) ? i : 0;
      sc[m][j] = (b[j] > a[j]) ? srcs[c] : 0;
    }
  for (int t = 0; t < mx; t += 32) {
    ushort8 gv[4][2];
#pragma unroll
    for (int m = 0; m < 4; ++m)
#pragma unroll
      for (int j = 0; j < 2; ++j)
        gv[m][j] = *(const ushort8*)(hb + (size_t)sc[m][j] * 64 + fs * 8);
    int pc[4][2];
    if (t + 32 < mx) {
#pragma unroll
      for (int m = 0; m < 4; ++m)
#pragma unroll
        for (int j = 0; j < 2; ++j) {
          int i = a[j] + t + 32 + m*8 + er;
          int c = (i < b[j]) ? i : 0;
          pc[m][j] = (b[j] > a[j]) ? srcs[c] : 0;
        }
    } else {
#pragma unroll
      for (int m = 0; m < 4; ++m)
#pragma unroll
        for (int j = 0; j < 2; ++j) pc[m][j] = 0;
    }
#pragma unroll
    for (int m = 0; m < 4; ++m)
#pragma unroll
      for (int j = 0; j < 2; ++j) {
        int i = a[j] + t + m*8 + er;
        if (i < b[j]) {
#pragma unroll
          for (int q = 0; q < 8; ++q) ag[j][q] += us2f(gv[m][j][q]);
        }
      }
#pragma unroll
    for (int m = 0; m < 4; ++m)
#pragma unroll
      for (int j = 0; j < 2; ++j) sc[m][j] = pc[m][j];
  }
#pragma unroll
  for (int j = 0; j < 2; ++j)
#pragma unroll
    for (int q = 0; q < 8; ++q) {
      float u = ag[j][q];
      u += __shfl_xor(u, 8); u += __shfl_xor(u, 16); u += __shfl_xor(u, 32);
      ag[j][q] = u;
    }
  if (er == 0) {
#pragma unroll
    for (int j = 0; j < 2; ++j) {
      int n = n0 + j;
      if (n < nNodes) {
        f32x4 lo = {ag[j][0], ag[j][1], ag[j][2], ag[j][3]};
        f32x4 hi = {ag[j][4], ag[j][5], ag[j][6], ag[j][7]};
        *(f32x4*)(G + (size_t)n * 64 + fs * 8) = lo;
        *(f32x4*)(G + (size_t)n * 64 + fs * 8 + 4) = hi;
      }
    }
  }
}

// ---------------- dense layer: MFMA (gi & gh) + GRU, fully streaming ----------------
__global__ __launch_bounds__(256) void layer_dense(
    const float* __restrict__ h_old, const float* __restrict__ Esum,
    const float* __restrict__ G, const int* __restrict__ deg,
    const short* __restrict__ WceH, const short* __restrict__ WceL,
    const short* __restrict__ WchH, const short* __restrict__ WchL,
    const short* __restrict__ whhH, const short* __restrict__ whhL,
    const float* __restrict__ bihA, const float* __restrict__ bih,
    const float* __restrict__ bhh, float* __restrict__ h_new,
    unsigned short* __restrict__ h_newb, int nNodes) {
  int tid = threadIdx.x, lane = tid & 63, w = tid >> 6;
  int lr = lane & 15, lg = lane >> 4;
  int nb = blockIdx.x * 64;

  int arow = nb + w*16 + lr; if (arow >= nNodes) arow = nNodes - 1;
  short8 EsH[2], EsL[2], GHf[2], GLf[2], HH[2], HL[2];
#pragma unroll
  for (int kk = 0; kk < 2; ++kk) {
    split8(Esum + (size_t)arow*64 + kk*32 + lg*8, EsH[kk], EsL[kk]);
    split8(G + (size_t)arow*64 + kk*32 + lg*8, GHf[kk], GLf[kk]);
    split8(h_old + (size_t)arow*64 + kk*32 + lg*8, HH[kk], HL[kk]);
  }

  int row0 = nb + w*16 + lg*4;
  float degv[4];
#pragma unroll
  for (int i = 0; i < 4; ++i) {
    int n = row0 + i;
    degv[i] = (n < nNodes) ? (float)deg[n] : 0.f;
  }

  f32x4 gi[12], gh[12];
#pragma unroll
  for (int ct = 0; ct < 12; ++ct) {
    float bi = bih[ct*16 + lr], ba = bihA[ct*16 + lr], bh = bhh[ct*16 + lr];
#pragma unroll
    for (int i = 0; i < 4; ++i) { gi[ct][i] = bi + degv[i]*ba; gh[ct][i] = bh; }
  }

#pragma unroll
  for (int ct = 0; ct < 12; ++ct) {
    int wb = (ct*16 + lr)*64 + lg*8;
#pragma unroll
    for (int kk = 0; kk < 2; ++kk) {
      int o = wb + kk*32;
      short8 wceh = *(const short8*)(WceH + o);
      short8 wcel = *(const short8*)(WceL + o);
      short8 wchh = *(const short8*)(WchH + o);
      short8 wchl = *(const short8*)(WchL + o);
      short8 whh_h = *(const short8*)(whhH + o);
      short8 whh_l = *(const short8*)(whhL + o);
      gi[ct] = __builtin_amdgcn_mfma_f32_16x16x32_bf16(EsH[kk], wceh, gi[ct], 0,0,0);
      gi[ct] = __builtin_amdgcn_mfma_f32_16x16x32_bf16(EsL[kk], wceh, gi[ct], 0,0,0);
      gi[ct] = __builtin_amdgcn_mfma_f32_16x16x32_bf16(EsH[kk], wcel, gi[ct], 0,0,0);
      gi[ct] = __builtin_amdgcn_mfma_f32_16x16x32_bf16(GHf[kk], wchh, gi[ct], 0,0,0);
      gi[ct] = __builtin_amdgcn_mfma_f32_16x16x32_bf16(GLf[kk], wchh, gi[ct], 0,0,0);
      gi[ct] = __builtin_amdgcn_mfma_f32_16x16x32_bf16(GHf[kk], wchl, gi[ct], 0,0,0);
      gh[ct] = __builtin_amdgcn_mfma_f32_16x16x32_bf16(HH[kk], whh_h, gh[ct], 0,0,0);
      gh[ct] = __builtin_amdgcn_mfma_f32_16x16x32_bf16(HL[kk], whh_h, gh[ct], 0,0,0);
      gh[ct] = __builtin_amdgcn_mfma_f32_16x16x32_bf16(HH[kk], whh_l, gh[ct], 0,0,0);
    }
  }

#pragma unroll
  for (int ct = 0; ct < 4; ++ct)
#pragma unroll
    for (int i = 0; i < 4; ++i) {
      int n = row0 + i;
      if (n < nNodes) {
        int jh = ct*16 + lr;
        float r = 1.f/(1.f + expf(-(gi[ct][i] + gh[ct][i])));
        float z = 1.f/(1.f + expf(-(gi[ct+4][i] + gh[ct+4][i])));
        float nn = tanhf(gi[ct+8][i] + r * gh[ct+8][i]);
        float hv = h_old[(size_t)n*64 + jh];
        float hn = (1.f - z)*nn + z*hv;
        h_new[(size_t)n*64 + jh] = hn;
        h_newb[(size_t)n*64 + jh] = (unsigned short)f2bf(hn);
      }
    }
}

__global__ __launch_bounds__(256) void out_mlp(
    const float* __restrict__ h, const int* __restrict__ pm,
    const float* __restrict__ W1, const float* __restrict__ b1,
    const float* __restrict__ W2, const float* __restrict__ b2,
    float* __restrict__ out, int nPosts) {
  int tid = threadIdx.x;
  int lane = tid & 63;
  int p = blockIdx.x*4 + (tid >> 6);
  if (p >= nPosts) return;
  int n = pm[p];
  float v = h[(size_t)n*64 + lane];
  int row = lane & 31;
  float o = b1[row];
#pragma unroll
  for (int k = 0; k < 64; ++k) {
    float vb = __shfl(v, k);
    o += vb * W1[row*64 + k];
  }
  o = fmaxf(o, 0.f);
  float val = o * W2[row] * 0.5f;  // each row computed twice -> halve
#pragma unroll
  for (int offm = 32; offm > 0; offm >>= 1) val += __shfl_xor(val, offm);
  if (lane == 0) out[p] = 1.f/(1.f + expf(-(val + b2[0])));
}

static inline char* aln(char*& w, size_t bytes) {
  uintptr_t p = ((uintptr_t)w + 255) & ~(uintptr_t)255;
  char* r = (char*)p;
  w = r + bytes;
  return r;
}

extern "C" void kernel_launch(void* const* d_in, const int* in_sizes, int n_in,
                              void* d_out, int out_size, void* d_ws, size_t ws_size,
                              hipStream_t stream) {
  const float* X    = (const float*)d_in[0];
  const float* EA   = (const float*)d_in[1];
  const int*   EI   = (const int*)d_in[2];
  const int*   PM   = (const int*)d_in[3];
  const float* Wn   = (const float*)d_in[5];
  const float* bn   = (const float*)d_in[6];
  const float* We   = (const float*)d_in[7];
  const float* be   = (const float*)d_in[8];
  const float* Wagg = (const float*)d_in[9];
  const float* bagg = (const float*)d_in[10];
  const float* wih  = (const float*)d_in[11];
  const float* whh  = (const float*)d_in[12];
  const float* bih  = (const float*)d_in[13];
  const float* bhh  = (const float*)d_in[14];
  const float* W1   = (const float*)d_in[15];
  const float* b1   = (const float*)d_in[16];
  const float* W2   = (const float*)d_in[17];
  const float* b2   = (const float*)d_in[18];
  float* out = (float*)d_out;

  int nNodes = in_sizes[0] / 128;
  int nEdges = in_sizes[1] / 64;
  int nPosts = in_sizes[3];
  const int* src = EI;
  const int* dst = EI + nEdges;
  int nSB = (nNodes + 4095) / 4096;

  char* w = (char*)d_ws;
  float* h0   = (float*)aln(w, (size_t)nNodes * 64 * 4);
  float* h1   = (float*)aln(w, (size_t)nNodes * 64 * 4);
  unsigned short* h0b = (unsigned short*)aln(w, (size_t)nNodes * 64 * 2);
  unsigned short* h1b = (unsigned short*)aln(w, (size_t)nNodes * 64 * 2);
  float* Esum = (float*)aln(w, (size_t)nNodes * 64 * 4);
  float* G    = (float*)aln(w, (size_t)nNodes * 64 * 4);
  short* WceH = (short*)aln(w, 12288 * 2);
  short* WceL = (short*)aln(w, 12288 * 2);
  short* WchH = (short*)aln(w, 12288 * 2);
  short* WchL = (short*)aln(w, 12288 * 2);
  short* whhH = (short*)aln(w, 12288 * 2);
  short* whhL = (short*)aln(w, 12288 * 2);
  float* bihA = (float*)aln(w, 192 * 4);
  int*   off  = (int*)aln(w, (size_t)(nNodes + 1) * 4);
  int*   deg  = (int*)aln(w, (size_t)nNodes * 4);
  int*   cur  = (int*)aln(w, (size_t)nNodes * 4);
  int*   srcs = (int*)aln(w, (size_t)nEdges * 4);
  int*   bsum = (int*)aln(w, (size_t)nSB * 4);
  unsigned short* encb = (unsigned short*)aln(w, (size_t)nEdges * 64 * 2);

  hipMemsetAsync(deg, 0, (size_t)nNodes * 4, stream);
  hipMemsetAsync(cur, 0, (size_t)nNodes * 4, stream);

  hist_deg<<<2048, 256, 0, stream>>>(dst, deg, nEdges);
  scan_pass1<<<nSB, 256, 0, stream>>>(deg, bsum, nNodes);
  scan_pass3<<<nSB, 256, 0, stream>>>(deg, bsum, off, nNodes, nSB);

  node_encode<<<(nNodes + 63) / 64, 256, 0, stream>>>(X, Wn, bn, h0, h0b, nNodes);
  edge_mlp<<<(nEdges + 255) / 256, 256, 0, stream>>>(EA, We, be, src, dst, off, cur,
                                                     srcs, encb, nEdges);
  make_combos<<<48, 256, 0, stream>>>(wih, Wagg, bagg, whh,
                                      WceH, WceL, WchH, WchL, whhH, whhL, bihA);

  // layer 1: fused Esum + G
  seg_gather<<<(nNodes + 7) / 8, 256, 0, stream>>>(encb, h0b, off, srcs, Esum, G, nNodes);
  layer_dense<<<(nNodes + 63) / 64, 256, 0, stream>>>(
      h0, Esum, G, deg, WceH, WceL, WchH, WchL, whhH, whhL,
      bihA, bih, bhh, h1, h1b, nNodes);
  // layer 2
  gather_G<<<(nNodes + 7) / 8, 256, 0, stream>>>(h1b, off, srcs, G, nNodes);
  layer_dense<<<(nNodes + 63) / 64, 256, 0, stream>>>(
      h1, Esum, G, deg, WceH, WceL, WchH, WchL, whhH, whhL,
      bihA, bih, bhh, h0, h0b, nNodes);

  out_mlp<<<(nPosts + 3) / 4, 256, 0, stream>>>(h0, PM, W1, b1, W2, b2, out, nPosts);
}

// Round 13
// 738.718 us; speedup vs baseline: 1.2708x; 1.0229x over previous
//
#include <hip/hip_runtime.h>

using short8  = __attribute__((ext_vector_type(8))) short;
using ushort8 = __attribute__((ext_vector_type(8))) unsigned short;
using us4     = __attribute__((ext_vector_type(4))) unsigned short;
using f32x4   = __attribute__((ext_vector_type(4))) float;

static __device__ __forceinline__ short f2bf(float f) {
  unsigned u = __float_as_uint(f);
  u += 0x7fffu + ((u >> 16) & 1u);   // RNE to bf16
  return (short)(u >> 16);
}
static __device__ __forceinline__ float bf2f(short s) {
  return __uint_as_float(((unsigned)(unsigned short)s) << 16);
}
static __device__ __forceinline__ float us2f(unsigned short s) {
  return __uint_as_float(((unsigned)s) << 16);
}
static __device__ __forceinline__ short8 load8_bf16(const float* __restrict__ p) {
  const f32x4* q = (const f32x4*)p;
  f32x4 a = q[0], b = q[1];
  short8 r;
  r[0]=f2bf(a[0]); r[1]=f2bf(a[1]); r[2]=f2bf(a[2]); r[3]=f2bf(a[3]);
  r[4]=f2bf(b[0]); r[5]=f2bf(b[1]); r[6]=f2bf(b[2]); r[7]=f2bf(b[3]);
  return r;
}
// hi/lo bf16 split: v ~= hi + lo
static __device__ __forceinline__ void split8(const float* p, short8& hi, short8& lo) {
  const f32x4* q = (const f32x4*)p;
  f32x4 a = q[0], b = q[1];
  float v[8] = {a[0],a[1],a[2],a[3],b[0],b[1],b[2],b[3]};
#pragma unroll
  for (int j = 0; j < 8; ++j) {
    short h = f2bf(v[j]);
    hi[j] = h;
    lo[j] = f2bf(v[j] - bf2f(h));
  }
}

// ---------------- fused prologue: node_encode | make_combos | hist_deg ----------------
__global__ __launch_bounds__(256) void prep(
    const float* __restrict__ X, const float* __restrict__ Wn,
    const float* __restrict__ bn, float* __restrict__ h,
    unsigned short* __restrict__ hb, int nNodes, int nbNode,
    const float* __restrict__ wih, const float* __restrict__ Wagg,
    const float* __restrict__ bagg, const float* __restrict__ whh,
    short* __restrict__ WceH, short* __restrict__ WceL,
    short* __restrict__ WchH, short* __restrict__ WchL,
    short* __restrict__ whhH, short* __restrict__ whhL, float* __restrict__ bihA,
    const int* __restrict__ dst, int* __restrict__ deg, int nEdges) {
  int blk = blockIdx.x;
  int tid = threadIdx.x;
  if (blk < nbNode) {
    // ---- node encoder: h = relu(X @ Wn^T + bn), MFMA, A-split ----
    int lane = tid & 63, w = tid >> 6, lg = lane >> 4, lr = lane & 15;
    short8 bf[4][4];
#pragma unroll
    for (int t = 0; t < 4; ++t)
#pragma unroll
      for (int kk = 0; kk < 4; ++kk)
        bf[t][kk] = load8_bf16(Wn + (t*16+lr)*128 + kk*32 + lg*8);
    float bias[4];
#pragma unroll
    for (int t = 0; t < 4; ++t) bias[t] = bn[t*16+lr];

    int base = blk * 64 + w * 16;
    int arow = base + lr;
    int nn = arow < nNodes ? arow : nNodes - 1;
    f32x4 acc[4] = {};
#pragma unroll
    for (int kk = 0; kk < 4; ++kk) {
      short8 aH, aL;
      split8(X + (size_t)nn*128 + kk*32 + lg*8, aH, aL);
#pragma unroll
      for (int t = 0; t < 4; ++t) {
        acc[t] = __builtin_amdgcn_mfma_f32_16x16x32_bf16(aH, bf[t][kk], acc[t], 0, 0, 0);
        acc[t] = __builtin_amdgcn_mfma_f32_16x16x32_bf16(aL, bf[t][kk], acc[t], 0, 0, 0);
      }
    }
#pragma unroll
    for (int t = 0; t < 4; ++t)
#pragma unroll
      for (int i = 0; i < 4; ++i) {
        int orow = base + lg*4 + i;
        if (orow < nNodes) {
          float v = fmaxf(acc[t][i] + bias[t], 0.f);
          h[(size_t)orow*64 + t*16 + lr] = v;
          hb[(size_t)orow*64 + t*16 + lr] = (unsigned short)f2bf(v);
        }
      }
    return;
  }
  blk -= nbNode;
  if (blk < 48) {
    // ---- weight combos (hi/lo bf16 splits; Wce k-rows permuted) ----
    int idx = blk*256 + tid;
    if (idx < 12288) {
      int r = idx >> 6, k = idx & 63;
      float a = 0.f, b = 0.f;
      for (int j = 0; j < 64; ++j) {
        float ww = wih[r*64 + j];
        a += ww * Wagg[j*128 + k];
        b += ww * Wagg[j*128 + 64 + k];
      }
      short ah = f2bf(a);
      WchH[idx] = ah; WchL[idx] = f2bf(a - bf2f(ah));
      int kp = (k & 15) * 4 + (k >> 4);
      short bh = f2bf(b);
      WceH[r*64 + kp] = bh; WceL[r*64 + kp] = f2bf(b - bf2f(bh));
      float wv = whh[idx];
      short hh = f2bf(wv);
      whhH[idx] = hh; whhL[idx] = f2bf(wv - bf2f(hh));
      if (idx < 192) {
        float s = 0.f;
        for (int j = 0; j < 64; ++j) s += wih[idx*64 + j] * bagg[j];
        bihA[idx] = s;
      }
    }
    return;
  }
  blk -= 48;
  // ---- hist_deg ----
  for (int e = blk*256 + tid; e < nEdges; e += 2048*256)
    atomicAdd(&deg[dst[e]], 1);
}

// ---------------- scan (2 passes; pass3 computes its own block prefix) ----------------
__global__ __launch_bounds__(256) void scan_pass1(
    const int* __restrict__ deg, int* __restrict__ bsum, int n) {
  int b = blockIdx.x, tid = threadIdx.x;
  int base = b * 4096;
  int s = 0;
  for (int j = tid; j < 4096; j += 256) {
    int i = base + j;
    s += (i < n) ? deg[i] : 0;
  }
  __shared__ int ws[4];
#pragma unroll
  for (int o = 32; o; o >>= 1) s += __shfl_down(s, o);
  if ((tid & 63) == 0) ws[tid >> 6] = s;
  __syncthreads();
  if (tid == 0) bsum[b] = ws[0] + ws[1] + ws[2] + ws[3];
}

__global__ __launch_bounds__(256) void scan_pass3(
    const int* __restrict__ deg, const int* __restrict__ bsum,
    int* __restrict__ off, int n, int nBlocks) {
  int b = blockIdx.x, tid = threadIdx.x;
  int lane = tid & 63, w = tid >> 6;
  __shared__ int bpre_s;
  if (tid == 0) {
    int run = 0;
    for (int k = 0; k < b; ++k) run += bsum[k];
    bpre_s = run;
    if (b == nBlocks - 1) off[n] = run + bsum[b];
  }
  int base = b * 4096 + tid * 16;
  int d[16], tot = 0;
#pragma unroll
  for (int j = 0; j < 16; ++j) {
    d[j] = (base + j < n) ? deg[base + j] : 0;
    tot += d[j];
  }
  int s = tot;
#pragma unroll
  for (int o = 1; o < 64; o <<= 1) {
    int t = __shfl_up(s, o);
    if (lane >= o) s += t;
  }
  __shared__ int ws[4];
  if (lane == 63) ws[w] = s;
  __syncthreads();
  int wo = 0;
  for (int k = 0; k < 4; ++k) wo += (k < w) ? ws[k] : 0;
  int run = bpre_s + wo + s - tot;
#pragma unroll
  for (int j = 0; j < 16; ++j) {
    if (base + j < n) off[base + j] = run;
    run += d[j];
  }
}

// ---------------- edge MLP: 64 edges/wave, deg-as-cursor (atomicSub), MFMA ----
// enc feature f = t*16+c stored at position c*4+t (C-fragment layout).
__global__ __launch_bounds__(256) void edge_mlp(
    const float* __restrict__ EA, const float* __restrict__ We,
    const float* __restrict__ be, const int* __restrict__ src,
    const int* __restrict__ dst, const int* __restrict__ off,
    int* __restrict__ deg, int* __restrict__ srcs,
    unsigned short* __restrict__ encb, int nEdges) {
  int tid = threadIdx.x, lane = tid & 63, w = tid >> 6;
  int lr = lane & 15, lg = lane >> 4;

  short8 bf[4][2];
#pragma unroll
  for (int t = 0; t < 4; ++t)
#pragma unroll
    for (int kk = 0; kk < 2; ++kk)
      bf[t][kk] = load8_bf16(We + (t*16+lr)*64 + kk*32 + lg*8);
  float bias[4];
#pragma unroll
  for (int t = 0; t < 4; ++t) bias[t] = be[t*16+lr];

  int e0 = blockIdx.x * 256 + w * 64;   // this wave's 64 edges
  int pos_reg = 0;
  {
    int e = e0 + lane;
    if (e < nEdges) {
      int d = dst[e];
      int old = atomicSub(&deg[d], 1);   // deg doubles as cursor; consumed here
      pos_reg = off[d] + old - 1;
      srcs[pos_reg] = src[e];
    }
  }

  const float* pr[4];
#pragma unroll
  for (int rb = 0; rb < 4; ++rb) {
    int c = e0 + rb*16 + lr; if (c >= nEdges) c = nEdges - 1;
    pr[rb] = EA + (size_t)c * 64;
  }
  f32x4 acc[4][4] = {};
#pragma unroll
  for (int kk = 0; kk < 2; ++kk) {
    short8 a[4];
#pragma unroll
    for (int rb = 0; rb < 4; ++rb) a[rb] = load8_bf16(pr[rb] + kk*32 + lg*8);
#pragma unroll
    for (int rb = 0; rb < 4; ++rb)
#pragma unroll
      for (int t = 0; t < 4; ++t)
        acc[rb][t] = __builtin_amdgcn_mfma_f32_16x16x32_bf16(a[rb], bf[t][kk], acc[rb][t], 0,0,0);
  }
#pragma unroll
  for (int rb = 0; rb < 4; ++rb)
#pragma unroll
    for (int i = 0; i < 4; ++i) {
      int rloc = rb*16 + lg*4 + i;
      int e = e0 + rloc;
      int pos = __shfl(pos_reg, rloc);
      if (e < nEdges) {
        us4 v;
#pragma unroll
        for (int t = 0; t < 4; ++t)
          v[t] = (unsigned short)f2bf(fmaxf(acc[rb][t][i] + bias[t], 0.f));
        *(us4*)(encb + (size_t)pos*64 + lr*4) = v;
      }
    }
}

// ---------------- fused seg_sum + layer-1 h-gather (2 nodes/wave, 4-deep) ----------------
__global__ __launch_bounds__(256) void seg_gather(
    const unsigned short* __restrict__ encb, const unsigned short* __restrict__ hb,
    const int* __restrict__ off, const int* __restrict__ srcs,
    float* __restrict__ Esum, float* __restrict__ G, int nNodes) {
  int tid = threadIdx.x, lane = tid & 63, w = tid >> 6;
  int er = lane >> 3, fs = lane & 7;
  int n0 = (blockIdx.x * 4 + w) * 2;
  if (n0 >= nNodes) return;
  int a[2], b[2];
#pragma unroll
  for (int j = 0; j < 2; ++j) {
    int n = n0 + j;
    a[j] = (n < nNodes) ? off[n] : 0;
    b[j] = (n < nNodes) ? off[n + 1] : 0;
  }
  float ae[2][8], ag[2][8];
#pragma unroll
  for (int j = 0; j < 2; ++j)
#pragma unroll
    for (int q = 0; q < 8; ++q) { ae[j][q] = 0.f; ag[j][q] = 0.f; }
  int mx = b[0] - a[0];
  if (b[1] - a[1] > mx) mx = b[1] - a[1];

  int sc[4][2];
#pragma unroll
  for (int m = 0; m < 4; ++m)
#pragma unroll
    for (int j = 0; j < 2; ++j) {
      int i = a[j] + m*8 + er;
      int c = (i < b[j]) ? i : 0;
      sc[m][j] = (b[j] > a[j]) ? srcs[c] : 0;
    }
  for (int t = 0; t < mx; t += 32) {
    ushort8 ev[4][2], gv[4][2];
#pragma unroll
    for (int m = 0; m < 4; ++m)
#pragma unroll
      for (int j = 0; j < 2; ++j) {
        int i = a[j] + t + m*8 + er;
        int c = (i < b[j]) ? i : 0;
        ev[m][j] = *(const ushort8*)(encb + (size_t)c * 64 + fs * 8);
        gv[m][j] = *(const ushort8*)(hb + (size_t)sc[m][j] * 64 + fs * 8);
      }
    int pc[4][2];
    if (t + 32 < mx) {
#pragma unroll
      for (int m = 0; m < 4; ++m)
#pragma unroll
        for (int j = 0; j < 2; ++j) {
          int i = a[j] + t + 32 + m*8 + er;
          int c = (i < b[j]) ? i : 0;
          pc[m][j] = (b[j] > a[j]) ? srcs[c] : 0;
        }
    } else {
#pragma unroll
      for (int m = 0; m < 4; ++m)
#pragma unroll
        for (int j = 0; j < 2; ++j) pc[m][j] = 0;
    }
#pragma unroll
    for (int m = 0; m < 4; ++m)
#pragma unroll
      for (int j = 0; j < 2; ++j) {
        int i = a[j] + t + m*8 + er;
        if (i < b[j]) {
#pragma unroll
          for (int q = 0; q < 8; ++q) {
            ae[j][q] += us2f(ev[m][j][q]);
            ag[j][q] += us2f(gv[m][j][q]);
          }
        }
      }
#pragma unroll
    for (int m = 0; m < 4; ++m)
#pragma unroll
      for (int j = 0; j < 2; ++j) sc[m][j] = pc[m][j];
  }
#pragma unroll
  for (int j = 0; j < 2; ++j)
#pragma unroll
    for (int q = 0; q < 8; ++q) {
      float v = ae[j][q];
      v += __shfl_xor(v, 8); v += __shfl_xor(v, 16); v += __shfl_xor(v, 32);
      ae[j][q] = v;
      float u = ag[j][q];
      u += __shfl_xor(u, 8); u += __shfl_xor(u, 16); u += __shfl_xor(u, 32);
      ag[j][q] = u;
    }
  if (er == 0) {
#pragma unroll
    for (int j = 0; j < 2; ++j) {
      int n = n0 + j;
      if (n < nNodes) {
        f32x4 elo = {ae[j][0], ae[j][1], ae[j][2], ae[j][3]};
        f32x4 ehi = {ae[j][4], ae[j][5], ae[j][6], ae[j][7]};
        *(f32x4*)(Esum + (size_t)n * 64 + fs * 8) = elo;
        *(f32x4*)(Esum + (size_t)n * 64 + fs * 8 + 4) = ehi;
        f32x4 glo = {ag[j][0], ag[j][1], ag[j][2], ag[j][3]};
        f32x4 ghi = {ag[j][4], ag[j][5], ag[j][6], ag[j][7]};
        *(f32x4*)(G + (size_t)n * 64 + fs * 8) = glo;
        *(f32x4*)(G + (size_t)n * 64 + fs * 8 + 4) = ghi;
      }
    }
  }
}

// ---------------- h gather (layer 2): 2 nodes/wave, 4-deep pipelined ----------------
__global__ __launch_bounds__(256) void gather_G(
    const unsigned short* __restrict__ hb, const int* __restrict__ off,
    const int* __restrict__ srcs, float* __restrict__ G, int nNodes) {
  int tid = threadIdx.x, lane = tid & 63, w = tid >> 6;
  int er = lane >> 3, fs = lane & 7;
  int n0 = (blockIdx.x * 4 + w) * 2;
  if (n0 >= nNodes) return;
  int a[2], b[2];
#pragma unroll
  for (int j = 0; j < 2; ++j) {
    int n = n0 + j;
    a[j] = (n < nNodes) ? off[n] : 0;
    b[j] = (n < nNodes) ? off[n + 1] : 0;
  }
  float ag[2][8];
#pragma unroll
  for (int j = 0; j < 2; ++j)
#pragma unroll
    for (int q = 0; q < 8; ++q) ag[j][q] = 0.f;
  int mx = b[0] - a[0];
  if (b[1] - a[1] > mx) mx = b[1] - a[1];

  int sc[4][2];
#pragma unroll
  for (int m = 0; m < 4; ++m)
#pragma unroll
    for (int j = 0; j < 2; ++j) {
      int i = a[j] + m*8 + er;
      int c = (i < b[j]) ? i : 0;
      sc[m][j] = (b[j] > a[j]) ? srcs[c] : 0;
    }
  for (int t = 0; t < mx; t += 32) {
    ushort8 gv[4][2];
#pragma unroll
    for (int m = 0; m < 4; ++m)
#pragma unroll
      for (int j = 0; j < 2; ++j)
        gv[m][j] = *(const ushort8*)(hb + (size_t)sc[m][j] * 64 + fs * 8);
    int pc[4][2];
    if (t + 32 < mx) {
#pragma unroll
      for (int m = 0; m < 4; ++m)
#pragma unroll
        for (int j = 0; j < 2; ++j) {
          int i = a[j] + t + 32 + m*8 + er;
          int c = (i < b[j]) ? i : 0;
          pc[m][j] = (b[j] > a[j]) ? srcs[c] : 0;
        }
    } else {
#pragma unroll
      for (int m = 0; m < 4; ++m)
#pragma unroll
        for (int j = 0; j < 2; ++j) pc[m][j] = 0;
    }
#pragma unroll
    for (int m = 0; m < 4; ++m)
#pragma unroll
      for (int j = 0; j < 2; ++j) {
        int i = a[j] + t + m*8 + er;
        if (i < b[j]) {
#pragma unroll
          for (int q = 0; q < 8; ++q) ag[j][q] += us2f(gv[m][j][q]);
        }
      }
#pragma unroll
    for (int m = 0; m < 4; ++m)
#pragma unroll
      for (int j = 0; j < 2; ++j) sc[m][j] = pc[m][j];
  }
#pragma unroll
  for (int j = 0; j < 2; ++j)
#pragma unroll
    for (int q = 0; q < 8; ++q) {
      float u = ag[j][q];
      u += __shfl_xor(u, 8); u += __shfl_xor(u, 16); u += __shfl_xor(u, 32);
      ag[j][q] = u;
    }
  if (er == 0) {
#pragma unroll
    for (int j = 0; j < 2; ++j) {
      int n = n0 + j;
      if (n < nNodes) {
        f32x4 lo = {ag[j][0], ag[j][1], ag[j][2], ag[j][3]};
        f32x4 hi = {ag[j][4], ag[j][5], ag[j][6], ag[j][7]};
        *(f32x4*)(G + (size_t)n * 64 + fs * 8) = lo;
        *(f32x4*)(G + (size_t)n * 64 + fs * 8 + 4) = hi;
      }
    }
  }
}

// ---------------- dense layer: MFMA (gi & gh) + GRU, fully streaming ----------------
__global__ __launch_bounds__(256) void layer_dense(
    const float* __restrict__ h_old, const float* __restrict__ Esum,
    const float* __restrict__ G, const int* __restrict__ off,
    const short* __restrict__ WceH, const short* __restrict__ WceL,
    const short* __restrict__ WchH, const short* __restrict__ WchL,
    const short* __restrict__ whhH, const short* __restrict__ whhL,
    const float* __restrict__ bihA, const float* __restrict__ bih,
    const float* __restrict__ bhh, float* __restrict__ h_new,
    unsigned short* __restrict__ h_newb, int nNodes) {
  int tid = threadIdx.x, lane = tid & 63, w = tid >> 6;
  int lr = lane & 15, lg = lane >> 4;
  int nb = blockIdx.x * 64;

  int arow = nb + w*16 + lr; if (arow >= nNodes) arow = nNodes - 1;
  short8 EsH[2], EsL[2], GHf[2], GLf[2], HH[2], HL[2];
#pragma unroll
  for (int kk = 0; kk < 2; ++kk) {
    split8(Esum + (size_t)arow*64 + kk*32 + lg*8, EsH[kk], EsL[kk]);
    split8(G + (size_t)arow*64 + kk*32 + lg*8, GHf[kk], GLf[kk]);
    split8(h_old + (size_t)arow*64 + kk*32 + lg*8, HH[kk], HL[kk]);
  }

  int row0 = nb + w*16 + lg*4;
  float degv[4];
#pragma unroll
  for (int i = 0; i < 4; ++i) {
    int n = row0 + i;
    degv[i] = (n < nNodes) ? (float)(off[n + 1] - off[n]) : 0.f;
  }

  f32x4 gi[12], gh[12];
#pragma unroll
  for (int ct = 0; ct < 12; ++ct) {
    float bi = bih[ct*16 + lr], ba = bihA[ct*16 + lr], bh = bhh[ct*16 + lr];
#pragma unroll
    for (int i = 0; i < 4; ++i) { gi[ct][i] = bi + degv[i]*ba; gh[ct][i] = bh; }
  }

#pragma unroll
  for (int ct = 0; ct < 12; ++ct) {
    int wb = (ct*16 + lr)*64 + lg*8;
#pragma unroll
    for (int kk = 0; kk < 2; ++kk) {
      int o = wb + kk*32;
      short8 wceh = *(const short8*)(WceH + o);
      short8 wcel = *(const short8*)(WceL + o);
      short8 wchh = *(const short8*)(WchH + o);
      short8 wchl = *(const short8*)(WchL + o);
      short8 whh_h = *(const short8*)(whhH + o);
      short8 whh_l = *(const short8*)(whhL + o);
      gi[ct] = __builtin_amdgcn_mfma_f32_16x16x32_bf16(EsH[kk], wceh, gi[ct], 0,0,0);
      gi[ct] = __builtin_amdgcn_mfma_f32_16x16x32_bf16(EsL[kk], wceh, gi[ct], 0,0,0);
      gi[ct] = __builtin_amdgcn_mfma_f32_16x16x32_bf16(EsH[kk], wcel, gi[ct], 0,0,0);
      gi[ct] = __builtin_amdgcn_mfma_f32_16x16x32_bf16(GHf[kk], wchh, gi[ct], 0,0,0);
      gi[ct] = __builtin_amdgcn_mfma_f32_16x16x32_bf16(GLf[kk], wchh, gi[ct], 0,0,0);
      gi[ct] = __builtin_amdgcn_mfma_f32_16x16x32_bf16(GHf[kk], wchl, gi[ct], 0,0,0);
      gh[ct] = __builtin_amdgcn_mfma_f32_16x16x32_bf16(HH[kk], whh_h, gh[ct], 0,0,0);
      gh[ct] = __builtin_amdgcn_mfma_f32_16x16x32_bf16(HL[kk], whh_h, gh[ct], 0,0,0);
      gh[ct] = __builtin_amdgcn_mfma_f32_16x16x32_bf16(HH[kk], whh_l, gh[ct], 0,0,0);
    }
  }

#pragma unroll
  for (int ct = 0; ct < 4; ++ct)
#pragma unroll
    for (int i = 0; i < 4; ++i) {
      int n = row0 + i;
      if (n < nNodes) {
        int jh = ct*16 + lr;
        float r = 1.f/(1.f + expf(-(gi[ct][i] + gh[ct][i])));
        float z = 1.f/(1.f + expf(-(gi[ct+4][i] + gh[ct+4][i])));
        float nn = tanhf(gi[ct+8][i] + r * gh[ct+8][i]);
        float hv = h_old[(size_t)n*64 + jh];
        float hn = (1.f - z)*nn + z*hv;
        h_new[(size_t)n*64 + jh] = hn;
        h_newb[(size_t)n*64 + jh] = (unsigned short)f2bf(hn);
      }
    }
}

__global__ __launch_bounds__(256) void out_mlp(
    const float* __restrict__ h, const int* __restrict__ pm,
    const float* __restrict__ W1, const float* __restrict__ b1,
    const float* __restrict__ W2, const float* __restrict__ b2,
    float* __restrict__ out, int nPosts) {
  int tid = threadIdx.x;
  int lane = tid & 63;
  int p = blockIdx.x*4 + (tid >> 6);
  if (p >= nPosts) return;
  int n = pm[p];
  float v = h[(size_t)n*64 + lane];
  int row = lane & 31;
  float o = b1[row];
#pragma unroll
  for (int k = 0; k < 64; ++k) {
    float vb = __shfl(v, k);
    o += vb * W1[row*64 + k];
  }
  o = fmaxf(o, 0.f);
  float val = o * W2[row] * 0.5f;  // each row computed twice -> halve
#pragma unroll
  for (int offm = 32; offm > 0; offm >>= 1) val += __shfl_xor(val, offm);
  if (lane == 0) out[p] = 1.f/(1.f + expf(-(val + b2[0])));
}

static inline char* aln(char*& w, size_t bytes) {
  uintptr_t p = ((uintptr_t)w + 255) & ~(uintptr_t)255;
  char* r = (char*)p;
  w = r + bytes;
  return r;
}

extern "C" void kernel_launch(void* const* d_in, const int* in_sizes, int n_in,
                              void* d_out, int out_size, void* d_ws, size_t ws_size,
                              hipStream_t stream) {
  const float* X    = (const float*)d_in[0];
  const float* EA   = (const float*)d_in[1];
  const int*   EI   = (const int*)d_in[2];
  const int*   PM   = (const int*)d_in[3];
  const float* Wn   = (const float*)d_in[5];
  const float* bn   = (const float*)d_in[6];
  const float* We   = (const float*)d_in[7];
  const float* be   = (const float*)d_in[8];
  const float* Wagg = (const float*)d_in[9];
  const float* bagg = (const float*)d_in[10];
  const float* wih  = (const float*)d_in[11];
  const float* whh  = (const float*)d_in[12];
  const float* bih  = (const float*)d_in[13];
  const float* bhh  = (const float*)d_in[14];
  const float* W1   = (const float*)d_in[15];
  const float* b1   = (const float*)d_in[16];
  const float* W2   = (const float*)d_in[17];
  const float* b2   = (const float*)d_in[18];
  float* out = (float*)d_out;

  int nNodes = in_sizes[0] / 128;
  int nEdges = in_sizes[1] / 64;
  int nPosts = in_sizes[3];
  const int* src = EI;
  const int* dst = EI + nEdges;
  int nSB = (nNodes + 4095) / 4096;
  int nbNode = (nNodes + 63) / 64;

  char* w = (char*)d_ws;
  float* h0   = (float*)aln(w, (size_t)nNodes * 64 * 4);
  float* h1   = (float*)aln(w, (size_t)nNodes * 64 * 4);
  unsigned short* h0b = (unsigned short*)aln(w, (size_t)nNodes * 64 * 2);
  unsigned short* h1b = (unsigned short*)aln(w, (size_t)nNodes * 64 * 2);
  float* Esum = (float*)aln(w, (size_t)nNodes * 64 * 4);
  float* G    = (float*)aln(w, (size_t)nNodes * 64 * 4);
  short* WceH = (short*)aln(w, 12288 * 2);
  short* WceL = (short*)aln(w, 12288 * 2);
  short* WchH = (short*)aln(w, 12288 * 2);
  short* WchL = (short*)aln(w, 12288 * 2);
  short* whhH = (short*)aln(w, 12288 * 2);
  short* whhL = (short*)aln(w, 12288 * 2);
  float* bihA = (float*)aln(w, 192 * 4);
  int*   off  = (int*)aln(w, (size_t)(nNodes + 1) * 4);
  int*   deg  = (int*)aln(w, (size_t)nNodes * 4);
  int*   srcs = (int*)aln(w, (size_t)nEdges * 4);
  int*   bsum = (int*)aln(w, (size_t)nSB * 4);
  unsigned short* encb = (unsigned short*)aln(w, (size_t)nEdges * 64 * 2);

  hipMemsetAsync(deg, 0, (size_t)nNodes * 4, stream);

  // fused prologue: node_encode | make_combos | hist_deg (all independent)
  prep<<<nbNode + 48 + 2048, 256, 0, stream>>>(
      X, Wn, bn, h0, h0b, nNodes, nbNode,
      wih, Wagg, bagg, whh, WceH, WceL, WchH, WchL, whhH, whhL, bihA,
      dst, deg, nEdges);

  scan_pass1<<<nSB, 256, 0, stream>>>(deg, bsum, nNodes);
  scan_pass3<<<nSB, 256, 0, stream>>>(deg, bsum, off, nNodes, nSB);

  // edge MLP consumes deg as its CSR cursor (atomicSub)
  edge_mlp<<<(nEdges + 255) / 256, 256, 0, stream>>>(EA, We, be, src, dst, off, deg,
                                                     srcs, encb, nEdges);

  // layer 1: fused Esum + G
  seg_gather<<<(nNodes + 7) / 8, 256, 0, stream>>>(encb, h0b, off, srcs, Esum, G, nNodes);
  layer_dense<<<(nNodes + 63) / 64, 256, 0, stream>>>(
      h0, Esum, G, off, WceH, WceL, WchH, WchL, whhH, whhL,
      bihA, bih, bhh, h1, h1b, nNodes);
  // layer 2
  gather_G<<<(nNodes + 7) / 8, 256, 0, stream>>>(h1b, off, srcs, G, nNodes);
  layer_dense<<<(nNodes + 63) / 64, 256, 0, stream>>>(
      h1, Esum, G, off, WceH, WceL, WchH, WchL, whhH, whhL,
      bihA, bih, bhh, h0, h0b, nNodes);

  out_mlp<<<(nPosts + 3) / 4, 256, 0, stream>>>(h0, PM, W1, b1, W2, b2, out, nPosts);
}